// Round 9
// baseline (679.760 us; speedup 1.0000x reference)
//
#include <hip/hip_runtime.h>

// TransFusion on MI355X — round 13.
// r12: KV gemm left top-5, but shortcut gemm grew to 110us — WRITE_SIZE
// 111MB shows the XOUT bounce (75.5MB store + 75.5MB re-read) was the cost.
// r13: fuse KV INTO the shortcut kernel (proj_kv). The 64x256 bf16 x1 tile
// is already in LDS: phase A = SC gelu(LN(x1@Wproj)) with per-tile 64-VGPR
// weight load; barrier (anti-hoist, r10); phase B = K|V = x1@Wkv in two
// n-halves (64-VGPR weight sets into the freed regs), written straight to
// REGA. Deletes XOUT store, KV kernel read, one dispatch. Peak VGPR ~124.
// Predict: proj_kv ~115-130us, total ~595us, absmax unchanged (same f2b'd
// staged values feed KV).

typedef unsigned short u16;
typedef unsigned int   u32;
typedef __bf16 bf16x8 __attribute__((ext_vector_type(8)));
typedef float  f32x4  __attribute__((ext_vector_type(4)));

__device__ __forceinline__ float b2f(u16 x) {
    union { u32 u; float f; } v; v.u = ((u32)x) << 16; return v.f;
}
__device__ __forceinline__ u16 f2b(float f) {
    union { float f; u32 u; } v; v.f = f;
    return (u16)((v.u + 0x7fffu + ((v.u >> 16) & 1u)) >> 16);
}
__device__ __forceinline__ u32 pk2(float x, float y) {
    return (u32)f2b(x) | ((u32)f2b(y) << 16);
}
// Branch-free A&S-7.1.26 gelu (~16 VALU, |err|<=1.5e-7).
__device__ __forceinline__ float gelu_fast(float x) {
    float z = x * 0.70710678118654752f;
    float a = fabsf(z);
    float t = __builtin_amdgcn_rcpf(fmaf(0.3275911f, a, 1.0f));
    float p = t*(0.254829592f + t*(-0.284496736f + t*(1.421413741f
              + t*(-1.453152027f + t*1.061405429f))));
    float e = __expf(-a*a);
    float er = copysignf(fmaf(-p, e, 1.0f), z);
    return 0.5f * x * (1.0f + er);
}
__device__ __forceinline__ void unpack8(uint4 r, float* v) {
    v[0] = b2f((u16)(r.x & 0xffff)); v[1] = b2f((u16)(r.x >> 16));
    v[2] = b2f((u16)(r.y & 0xffff)); v[3] = b2f((u16)(r.y >> 16));
    v[4] = b2f((u16)(r.z & 0xffff)); v[5] = b2f((u16)(r.z >> 16));
    v[6] = b2f((u16)(r.w & 0xffff)); v[7] = b2f((u16)(r.w >> 16));
}
__device__ __forceinline__ uint4 pack8(const float* v) {
    uint4 r;
    r.x = (u32)f2b(v[0]) | ((u32)f2b(v[1]) << 16);
    r.y = (u32)f2b(v[2]) | ((u32)f2b(v[3]) << 16);
    r.z = (u32)f2b(v[4]) | ((u32)f2b(v[5]) << 16);
    r.w = (u32)f2b(v[6]) | ((u32)f2b(v[7]) << 16);
    return r;
}

// ------------- one-time weight prep: f32 W[K][N] -> bf16 Wt[N][K] -----------
__launch_bounds__(256)
__global__ void setup_weights(const float* Wq, const float* Wk, const float* Wv,
    const float* Wq2, const float* Wk2, const float* Wv2, const float* Wproj,
    const float* Wfc1, const float* Wfc2, const float* bk, const float* bv,
    const float* bk2, const float* bv2,
    u16* wt_proj, u16* wt_kv, u16* wt_q, u16* wt_fc1, u16* wt_fc2,
    u16* wt_q2, u16* wt_k2v2, float* bkv, float* bk2v2)
{
    long i = (long)blockIdx.x*256 + threadIdx.x;
    if (i < 32768) { int k=(int)(i>>7), n=(int)(i&127); wt_proj[n*256+k]=f2b(Wproj[i]); return; } i -= 32768;
    if (i < 32768) { int k=(int)(i>>7), n=(int)(i&127); wt_kv[n*256+k]=f2b(Wk[i]); return; } i -= 32768;
    if (i < 32768) { int k=(int)(i>>7), n=(int)(i&127); wt_kv[(128+n)*256+k]=f2b(Wv[i]); return; } i -= 32768;
    if (i < 16384) { int k=(int)(i>>7), n=(int)(i&127); wt_q[n*128+k]=f2b(Wq[i]); return; } i -= 16384;
    if (i < 32768) { int k=(int)(i>>8), n=(int)(i&255); wt_fc1[n*128+k]=f2b(Wfc1[i]); return; } i -= 32768;
    if (i < 32768) { int k=(int)(i>>7), n=(int)(i&127); wt_fc2[n*256+k]=f2b(Wfc2[i]); return; } i -= 32768;
    if (i < 16384) { int k=(int)(i>>7), n=(int)(i&127); wt_q2[n*128+k]=f2b(Wq2[i]); return; } i -= 16384;
    if (i < 32768) { int k=(int)(i>>7), n=(int)(i&127); wt_k2v2[n*256+k]=f2b(Wk2[i]); return; } i -= 32768;
    if (i < 32768) { int k=(int)(i>>7), n=(int)(i&127); wt_k2v2[(128+n)*256+k]=f2b(Wv2[i]); return; } i -= 32768;
    if (i < 128) { bkv[i]=bk[i]; return; } i -= 128;
    if (i < 128) { bkv[128+i]=bv[i]; return; } i -= 128;
    if (i < 128) { bk2v2[i]=bk2[i]; return; } i -= 128;
    if (i < 128) { bk2v2[128+i]=bv2[i]; return; }
}

// ------ fused x1 projections: SC = gelu(LN(x1@Wproj+b)), KV = x1@Wkv+b ------
// One NCHW staging of the 64x256 x1 tile feeds BOTH projections.
// Phase A: NT=2 (64-VGPR WTPROJ slice, loaded per tile), EPI=2 -> SC.
// Phase B: two n-halves of WTKV (64-VGPR each, loaded into freed regs after
// the phase barrier), EPI=0 -> KV. No weight sets coexist; peak ~124 VGPR.
__launch_bounds__(256)
__global__ void proj_kv(const float* __restrict__ Af,
                        const u16* __restrict__ WtP, const float* __restrict__ biasP,
                        const float* __restrict__ gw, const float* __restrict__ bw,
                        const u16* __restrict__ WtKV, const float* __restrict__ biasKV,
                        u16* __restrict__ outSC, u16* __restrict__ outKV, int nTiles)
{
    constexpr int KD = 256, AST = KD + 8;
    __shared__ alignas(16) u16 a_sm[64*AST];
    __shared__ float pls[256], plq[256];
    const int t = threadIdx.x, w = t>>6, lane = t&63, lrow = lane&15, quad = lane>>4;

    for (int tile = blockIdx.x; tile < nTiles; tile += gridDim.x) {
        const long row0 = (long)tile*64;
        __syncthreads();
        {   // NCHW staging, 2-channel packed (r11)
            const int bb = (int)(row0/36864); const long p0 = row0 % 36864;
            const int c0 = (t>>3)*2, pj = (t&7)*8;
#pragma unroll
            for (int cc = 0; cc < 4; cc++) {
                int c = c0 + cc*64;
                const float* s0 = Af + ((long)bb*KD + c)*36864 + p0 + pj;
                const float* s1 = s0 + 36864;
                float4 a0 = *(const float4*)s0, a1 = *(const float4*)(s0+4);
                float4 b0 = *(const float4*)s1, b1 = *(const float4*)(s1+4);
                *(u32*)&a_sm[(pj+0)*AST + c] = pk2(a0.x, b0.x);
                *(u32*)&a_sm[(pj+1)*AST + c] = pk2(a0.y, b0.y);
                *(u32*)&a_sm[(pj+2)*AST + c] = pk2(a0.z, b0.z);
                *(u32*)&a_sm[(pj+3)*AST + c] = pk2(a0.w, b0.w);
                *(u32*)&a_sm[(pj+4)*AST + c] = pk2(a1.x, b1.x);
                *(u32*)&a_sm[(pj+5)*AST + c] = pk2(a1.y, b1.y);
                *(u32*)&a_sm[(pj+6)*AST + c] = pk2(a1.z, b1.z);
                *(u32*)&a_sm[(pj+7)*AST + c] = pk2(a1.w, b1.w);
            }
        }
        __syncthreads();

        // ---- phase A: shortcut (ND=128, NT=2), weights loaded per tile ----
        {
            bf16x8 WBp[2][8];
            float bcolp[2], gcol[2], bwcol[2];
#pragma unroll
            for (int n = 0; n < 2; n++) {
                int col = w*32 + n*16 + lrow;
#pragma unroll
                for (int k = 0; k < 8; k++)
                    WBp[n][k] = *(const bf16x8*)&WtP[(size_t)col*KD + k*32 + quad*8];
                bcolp[n] = biasP[col]; gcol[n] = gw[col]; bwcol[n] = bw[col];
            }
            f32x4 acc[4][2];
#pragma unroll
            for (int rt = 0; rt < 4; rt++)
#pragma unroll
                for (int n = 0; n < 2; n++) { f32x4 z = {0.f,0.f,0.f,0.f}; acc[rt][n] = z; }
#pragma unroll
            for (int rt = 0; rt < 4; rt++) {
                bf16x8 af[8];
#pragma unroll
                for (int k = 0; k < 8; k++)
                    af[k] = *(const bf16x8*)&a_sm[(rt*16+lrow)*AST + k*32 + quad*8];
#pragma unroll
                for (int n = 0; n < 2; n++)
#pragma unroll
                    for (int k = 0; k < 8; k++)
                        acc[rt][n] = __builtin_amdgcn_mfma_f32_16x16x32_bf16(af[k], WBp[n][k], acc[rt][n], 0, 0, 0);
            }
#pragma unroll
            for (int rt = 0; rt < 4; rt++)
#pragma unroll
                for (int r = 0; r < 4; r++) {
                    float s = 0.f, sq = 0.f;
#pragma unroll
                    for (int n = 0; n < 2; n++) {
                        float v = acc[rt][n][r] + bcolp[n];
                        acc[rt][n][r] = v; s += v; sq += v*v;
                    }
#pragma unroll
                    for (int off = 1; off < 16; off <<= 1) { s += __shfl_xor(s, off); sq += __shfl_xor(sq, off); }
                    if (lrow == 0) { int ri = rt*16 + quad*4 + r; pls[w*64+ri] = s; plq[w*64+ri] = sq; }
                }
            __syncthreads();
#pragma unroll
            for (int rt = 0; rt < 4; rt++)
#pragma unroll
                for (int r = 0; r < 4; r++) {
                    int ri = rt*16 + quad*4 + r;
                    float s  = pls[ri] + pls[64+ri] + pls[128+ri] + pls[192+ri];
                    float sq = plq[ri] + plq[64+ri] + plq[128+ri] + plq[192+ri];
                    float mean = s*(1.0f/128.0f);
                    float var = sq*(1.0f/128.0f) - mean*mean;
                    float rstd = rsqrtf(var + 1e-5f);
#pragma unroll
                    for (int n = 0; n < 2; n++) {
                        int col = w*32 + n*16 + lrow;
                        float y = (acc[rt][n][r]-mean)*rstd*gcol[n] + bwcol[n];
                        outSC[(row0+ri)*128 + col] = f2b(gelu_fast(y));
                    }
                }
        }
        __syncthreads();   // phase boundary: WBp dead; KV weight loads can't hoist

        // ---- phase B: K|V (ND=256) in two n-halves, 64-VGPR weights each ----
#pragma unroll
        for (int nh = 0; nh < 2; nh++) {
            bf16x8 WBk[2][8];
            float bcolk[2];
#pragma unroll
            for (int n = 0; n < 2; n++) {
                int col = w*64 + nh*32 + n*16 + lrow;
#pragma unroll
                for (int k = 0; k < 8; k++)
                    WBk[n][k] = *(const bf16x8*)&WtKV[(size_t)col*KD + k*32 + quad*8];
                bcolk[n] = biasKV[col];
            }
#pragma unroll
            for (int rt = 0; rt < 4; rt++) {
                bf16x8 af[8];
#pragma unroll
                for (int k = 0; k < 8; k++)
                    af[k] = *(const bf16x8*)&a_sm[(rt*16+lrow)*AST + k*32 + quad*8];
                f32x4 acc[2];
#pragma unroll
                for (int n = 0; n < 2; n++) { f32x4 z = {0.f,0.f,0.f,0.f}; acc[n] = z; }
#pragma unroll
                for (int n = 0; n < 2; n++)
#pragma unroll
                    for (int k = 0; k < 8; k++)
                        acc[n] = __builtin_amdgcn_mfma_f32_16x16x32_bf16(af[k], WBk[n][k], acc[n], 0, 0, 0);
#pragma unroll
                for (int n = 0; n < 2; n++) {
                    int col = w*64 + nh*32 + n*16 + lrow;
#pragma unroll
                    for (int r = 0; r < 4; r++)
                        outKV[(row0 + rt*16 + quad*4 + r)*256 + col] = f2b(acc[n][r] + bcolk[n]);
                }
            }
        }
    }
}

// ---------------- register-weight MFMA GEMM ---------------------------------
// out[r][n] = epi(A[r][:] @ Wt[n][:] + bias[n]); 64-row tiles, grid-stride.
// NCHW_IN=1: A = Af (f32 [bb][KD][36864]); else A = Ab (bf16 row-major [*][KD]).
// EPI 0: bf16 out = (acc+bias)*scale.
template<int KD, int ND, int EPI, int NCHW_IN>
__launch_bounds__(256)
__global__ void gemm_rw(const float* __restrict__ Af, const u16* __restrict__ Ab,
                        const u16* __restrict__ Wt, const float* __restrict__ bias,
                        u16* __restrict__ out, float scale, int nTiles)
{
    constexpr int KS = KD/32, NW = ND/4, NT = NW/16, AST = KD + 8;
    __shared__ alignas(16) u16 a_sm[64*AST];
    const int t = threadIdx.x, w = t>>6, lane = t&63, lrow = lane&15, quad = lane>>4;

    bf16x8 WB[NT][KS];
    float bcol[NT];
#pragma unroll
    for (int n = 0; n < NT; n++) {
        int col = w*NW + n*16 + lrow;
#pragma unroll
        for (int k = 0; k < KS; k++)
            WB[n][k] = *(const bf16x8*)&Wt[(size_t)col*KD + k*32 + quad*8];
        bcol[n] = bias[col];
    }

    for (int tile = blockIdx.x; tile < nTiles; tile += gridDim.x) {
        const long row0 = (long)tile*64;
        __syncthreads();
        if (NCHW_IN) {
            const int bb = (int)(row0/36864); const long p0 = row0 % 36864;
            const int c0 = (t>>3)*2, pj = (t&7)*8;
#pragma unroll
            for (int cc = 0; cc < KD/64; cc++) {
                int c = c0 + cc*64;
                const float* s0 = Af + ((long)bb*KD + c)*36864 + p0 + pj;
                const float* s1 = s0 + 36864;
                float4 a0 = *(const float4*)s0, a1 = *(const float4*)(s0+4);
                float4 b0 = *(const float4*)s1, b1 = *(const float4*)(s1+4);
                *(u32*)&a_sm[(pj+0)*AST + c] = pk2(a0.x, b0.x);
                *(u32*)&a_sm[(pj+1)*AST + c] = pk2(a0.y, b0.y);
                *(u32*)&a_sm[(pj+2)*AST + c] = pk2(a0.z, b0.z);
                *(u32*)&a_sm[(pj+3)*AST + c] = pk2(a0.w, b0.w);
                *(u32*)&a_sm[(pj+4)*AST + c] = pk2(a1.x, b1.x);
                *(u32*)&a_sm[(pj+5)*AST + c] = pk2(a1.y, b1.y);
                *(u32*)&a_sm[(pj+6)*AST + c] = pk2(a1.z, b1.z);
                *(u32*)&a_sm[(pj+7)*AST + c] = pk2(a1.w, b1.w);
            }
        } else {
            const int am = t>>2, ak = (t&3)*(KD/4);
#pragma unroll
            for (int j = 0; j < KD/32; j++)
                *(uint4*)&a_sm[am*AST + ak + j*8] = *(const uint4*)&Ab[(row0+am)*KD + ak + j*8];
        }
        __syncthreads();

#pragma unroll
        for (int rt = 0; rt < 4; rt++) {
            bf16x8 af[KS];
#pragma unroll
            for (int k = 0; k < KS; k++)
                af[k] = *(const bf16x8*)&a_sm[(rt*16+lrow)*AST + k*32 + quad*8];
            f32x4 acc[NT];
#pragma unroll
            for (int n = 0; n < NT; n++) { f32x4 z = {0.f,0.f,0.f,0.f}; acc[n] = z; }
#pragma unroll
            for (int n = 0; n < NT; n++)
#pragma unroll
                for (int k = 0; k < KS; k++)
                    acc[n] = __builtin_amdgcn_mfma_f32_16x16x32_bf16(af[k], WB[n][k], acc[n], 0, 0, 0);
#pragma unroll
            for (int n = 0; n < NT; n++) {
                int col = w*NW + n*16 + lrow;
#pragma unroll
                for (int r = 0; r < 4; r++)
                    out[(row0 + rt*16 + quad*4 + r)*ND + col] = f2b((acc[n][r] + bcol[n]) * scale);
            }
        }
    }
}

// ---------------- 12x12 avgpool over f32 NCHW -> bf16 -----------------------
template<int C>
__launch_bounds__(256)
__global__ void avgpool_nchw(const float* __restrict__ X, u16* __restrict__ out)
{
    int blk = blockIdx.x;
    int bb = blk / C, c = blk % C;
    int t = threadIdx.x;
    int wy = t >> 4, wx = t & 15;
    const float* base = X + ((long)(bb*C + c))*36864;
    float s = 0.f;
    for (int py = 0; py < 12; py++) {
        long ro = (long)(wy*12+py)*192 + wx*12;
#pragma unroll
        for (int px = 0; px < 12; px++) s += base[ro + px];
    }
    out[((long)(bb*256 + t))*C + c] = f2b(s * (1.0f/144.0f));
}

// ---------------- global-path softmax attention (tiny) ----------------------
__launch_bounds__(256)
__global__ void global_attn(const u16* __restrict__ qg, const u16* __restrict__ kv,
                            float* __restrict__ qgo)
{
    int t = threadIdx.x;
    int wvq = t >> 6, lane = t & 63;
    int bid = blockIdx.x;
    int qb = bid & 63, bh = bid >> 6;
    int bb = bh >> 3, h = bh & 7;
    int q = qb*4 + wvq;

    const u16* qrow = qg + ((long)(bb*256 + q))*128 + h*16;
    float qv[16];
#pragma unroll
    for (int d = 0; d < 16; d++) qv[d] = b2f(qrow[d]);

    float s[4];
#pragma unroll
    for (int jj = 0; jj < 4; jj++) {
        int j = jj*64 + lane;
        const u16* krow = kv + ((long)(bb*256 + j))*256 + h*16;
        float a = 0.f;
#pragma unroll
        for (int d = 0; d < 16; d++) a += qv[d] * b2f(krow[d]);
        s[jj] = a;
    }
    float m = fmaxf(fmaxf(s[0], s[1]), fmaxf(s[2], s[3]));
#pragma unroll
    for (int off = 1; off < 64; off <<= 1) m = fmaxf(m, __shfl_xor(m, off));
    float p[4]; float lsum = 0.f;
#pragma unroll
    for (int jj = 0; jj < 4; jj++) { p[jj] = expf(s[jj] - m); lsum += p[jj]; }
#pragma unroll
    for (int off = 1; off < 64; off <<= 1) lsum += __shfl_xor(lsum, off);

    float acc[16];
#pragma unroll
    for (int d = 0; d < 16; d++) acc[d] = 0.f;
#pragma unroll
    for (int jj = 0; jj < 4; jj++) {
        int j = jj*64 + lane;
        const u16* vrow = kv + ((long)(bb*256 + j))*256 + 128 + h*16;
#pragma unroll
        for (int d = 0; d < 16; d++) acc[d] += p[jj] * b2f(vrow[d]);
    }
#pragma unroll
    for (int d = 0; d < 16; d++) {
        float x = acc[d];
#pragma unroll
        for (int off = 1; off < 64; off <<= 1) x += __shfl_xor(x, off);
        acc[d] = x;
    }
    if (lane == 0) {
        float inv = 1.0f / lsum;
        float* dst = qgo + ((long)(bb*256 + q))*128 + h*16;
#pragma unroll
        for (int d = 0; d < 16; d++) dst[d] = acc[d] * inv;
    }
}

// ---------------- per-window K^T V (16x16 per head) -------------------------
__launch_bounds__(256)
__global__ void window_kv(const u16* __restrict__ KV, float* __restrict__ KVw)
{
    __shared__ alignas(16) u16 kvs[72*256];
    int t = threadIdx.x;
    int wid = blockIdx.x;
    int bb = wid >> 8, wy = (wid >> 4) & 15, wx = wid & 15;
    int h = t >> 5, rem = t & 31, ii = rem >> 1, j0 = (rem & 1)*8;
    float acc[8];
#pragma unroll
    for (int j = 0; j < 8; j++) acc[j] = 0.f;

    for (int chunk = 0; chunk < 2; chunk++) {
        __syncthreads();
        for (int pass = 0; pass < 5; pass++) {
            int nn = pass*16 + (t >> 4);
            if (nn < 72) {
                int n = chunk*72 + nn;
                int py = n/12, px = n%12;
                long row = (long)bb*36864 + (long)(wy*12+py)*192 + wx*12+px;
                int ch = (t & 15)*16;
                *(uint4*)&kvs[nn*256 + ch]     = *(const uint4*)&KV[row*256 + ch];
                *(uint4*)&kvs[nn*256 + ch + 8] = *(const uint4*)&KV[row*256 + ch + 8];
            }
        }
        __syncthreads();
        for (int nn = 0; nn < 72; nn++) {
            float kvv = b2f(kvs[nn*256 + h*16 + ii]);
            uint4 vr = *(const uint4*)&kvs[nn*256 + 128 + h*16 + j0];
            float vv[8]; unpack8(vr, vv);
#pragma unroll
            for (int j = 0; j < 8; j++) acc[j] += kvv * vv[j];
        }
    }
    float* dst = KVw + (((long)wid*8 + h)*16 + ii)*16 + j0;
#pragma unroll
    for (int j = 0; j < 8; j++) dst[j] = acc[j];
}

// ---- per-window ql = Q@(K^T V), + bilinear-upsampled global out, + LN ------
__launch_bounds__(256)
__global__ void window_out(const u16* __restrict__ Q, const float* __restrict__ KVw,
                           const float* __restrict__ qgo, const float* __restrict__ gw,
                           const float* __restrict__ bw, u16* __restrict__ Hout)
{
    __shared__ alignas(16) u16 qs[144*136];
    __shared__ alignas(16) float kvs[8*264];
    int t = threadIdx.x;
    int wid = blockIdx.x;
    int bb = wid >> 8, wy = (wid >> 4) & 15, wx = wid & 15;

    for (int pass = 0; pass < 9; pass++) {
        int n = pass*16 + (t >> 4);
        int py = n/12, px = n%12;
        long row = (long)bb*36864 + (long)(wy*12+py)*192 + wx*12+px;
        int ch = (t & 15)*8;
        *(uint4*)&qs[n*136 + ch] = *(const uint4*)&Q[row*128 + ch];
    }
    {
        const float* src = KVw + (long)wid*2048;
        for (int e = t; e < 2048; e += 256) {
            int hh = e >> 8, rem2 = e & 255;
            kvs[hh*264 + rem2] = src[e];
        }
    }
    __syncthreads();
    int td = t & 15;
    int h = td & 7, j0 = (td >> 3)*8;
    int cbase = h*16 + j0;
    float gv8[8], bv8[8];
#pragma unroll
    for (int j = 0; j < 8; j++) { gv8[j] = gw[cbase+j]; bv8[j] = bw[cbase+j]; }

    for (int pass = 0; pass < 9; pass++) {
        int pi = pass*16 + (t >> 4);
        int py = pi/12, px = pi%12;
        int y = wy*12+py, x = wx*12+px;
        float acc[8];
#pragma unroll
        for (int j = 0; j < 8; j++) acc[j] = 0.f;
#pragma unroll
        for (int i = 0; i < 16; i++) {
            float qv = b2f(qs[pi*136 + h*16 + i]);
            const float* kp = &kvs[h*264 + i*16 + j0];
            float4 ka = *(const float4*)kp;
            float4 kb = *(const float4*)(kp + 4);
            acc[0] += qv*ka.x; acc[1] += qv*ka.y; acc[2] += qv*ka.z; acc[3] += qv*ka.w;
            acc[4] += qv*kb.x; acc[5] += qv*kb.y; acc[6] += qv*kb.z; acc[7] += qv*kb.w;
        }
        float syf = y * (15.0f/191.0f);
        int y0 = (int)syf; float fy = syf - y0; int y1 = min(y0+1, 15);
        float sxf = x * (15.0f/191.0f);
        int x0 = (int)sxf; float fx = sxf - x0; int x1 = min(x0+1, 15);
        const float* g00 = qgo + (((long)bb*16 + y0)*16 + x0)*128 + cbase;
        const float* g01 = qgo + (((long)bb*16 + y0)*16 + x1)*128 + cbase;
        const float* g10 = qgo + (((long)bb*16 + y1)*16 + x0)*128 + cbase;
        const float* g11 = qgo + (((long)bb*16 + y1)*16 + x1)*128 + cbase;
        float w00 = (1.f-fy)*(1.f-fx), w01 = (1.f-fy)*fx, w10 = fy*(1.f-fx), w11 = fy*fx;
        float v8[8];
        float sum = 0.f, sq = 0.f;
#pragma unroll
        for (int j = 0; j < 8; j++) {
            float gval = w00*g00[j] + w01*g01[j] + w10*g10[j] + w11*g11[j];
            float xv = acc[j] + gval;
            v8[j] = xv; sum += xv; sq += xv*xv;
        }
#pragma unroll
        for (int off = 1; off < 16; off <<= 1) { sum += __shfl_xor(sum, off); sq += __shfl_xor(sq, off); }
        float mean = sum * (1.0f/128.0f);
        float var = sq * (1.0f/128.0f) - mean*mean;
        float rstd = rsqrtf(var + 1e-5f);
        float o8[8];
#pragma unroll
        for (int j = 0; j < 8; j++) o8[j] = (v8[j]-mean)*rstd*gv8[j] + bv8[j];
        long orow = (long)bb*36864 + (long)y*192 + x;
        *(uint4*)&Hout[orow*128 + cbase] = pack8(o8);
    }
}

// ------- fused MLP: U = gelu(H@W1+b1)@W2+b2; out = LN(U+SC) -> f32 NCHW -----
// Phase-split weight residency (r10) + SC register prefetch (r11).
__launch_bounds__(256)
__global__ void mlp_fused(const u16* __restrict__ H, const u16* __restrict__ W1t,
                          const float* __restrict__ b1f, const u16* __restrict__ W2t,
                          const float* __restrict__ b2f32, const u16* __restrict__ SC,
                          const float* __restrict__ g2, const float* __restrict__ bt2,
                          float* __restrict__ out, int nTiles)
{
    __shared__ alignas(16) char sm[53248];
    u16* h_sm  = (u16*)sm;              // 64 x 136 u16 (17408 B)
    u16* t_sm  = (u16*)(sm + 17408);    // 64 x 264 u16 (33792 B)
    float* pls = (float*)(sm + 51200);  // 4 x 64
    float* plq = (float*)(sm + 52224);  // 4 x 64
    float* lt  = (float*)sm;            // 128 x 68 f32 (34816 B) — after phase 2

    const int t = threadIdx.x, w = t>>6, lane = t&63, lrow = lane&15, quad = lane>>4;

    const long row0 = (long)blockIdx.x*64;
    const int bb = (int)(row0/36864); const long p0 = row0 % 36864;

    // SC prefetch — issued first so the (L3-resident) loads drain under
    // phase 1. 32 VGPR live across the kernel; headroom exists (r10: 72).
    float scv[4][4][2];
#pragma unroll
    for (int rt = 0; rt < 4; rt++)
#pragma unroll
        for (int r = 0; r < 4; r++)
#pragma unroll
            for (int n = 0; n < 2; n++)
                scv[rt][r][n] = b2f(SC[(row0 + rt*16 + quad*4 + r)*128 + w*32 + n*16 + lrow]);

    // ---- phase-1 weights only (64 VGPR) ----
    bf16x8 WB1[4][4];
    float b1col[4];
#pragma unroll
    for (int n = 0; n < 4; n++) {
        int col = w*64 + n*16 + lrow;
#pragma unroll
        for (int k = 0; k < 4; k++)
            WB1[n][k] = *(const bf16x8*)&W1t[(size_t)col*128 + k*32 + quad*8];
        b1col[n] = b1f[col];
    }

    // stage H
    {
        const int am = t>>2, ak = (t&3)*32;
#pragma unroll
        for (int j = 0; j < 4; j++)
            *(uint4*)&h_sm[am*136 + ak + j*8] = *(const uint4*)&H[(row0+am)*128 + ak + j*8];
    }
    __syncthreads();

    // phase 1: T = gelu(H@W1+b1) -> t_sm
#pragma unroll
    for (int rt = 0; rt < 4; rt++) {
        bf16x8 af[4];
#pragma unroll
        for (int k = 0; k < 4; k++)
            af[k] = *(const bf16x8*)&h_sm[(rt*16+lrow)*136 + k*32 + quad*8];
        f32x4 a1[4];
#pragma unroll
        for (int n = 0; n < 4; n++) { f32x4 z = {0.f,0.f,0.f,0.f}; a1[n] = z; }
#pragma unroll
        for (int n = 0; n < 4; n++)
#pragma unroll
            for (int k = 0; k < 4; k++)
                a1[n] = __builtin_amdgcn_mfma_f32_16x16x32_bf16(af[k], WB1[n][k], a1[n], 0, 0, 0);
#pragma unroll
        for (int n = 0; n < 4; n++)
#pragma unroll
            for (int r = 0; r < 4; r++)
                t_sm[(rt*16+quad*4+r)*264 + w*64 + n*16 + lrow] = f2b(gelu_fast(a1[n][r] + b1col[n]));
    }
    __syncthreads();   // phase boundary: WB1 dead past here; loads below can't hoist

    // ---- phase-2 weights into the freed registers (64 VGPR) ----
    bf16x8 WB2[2][8];
    float b2col[2], gcol[2], bwcol[2];
#pragma unroll
    for (int n = 0; n < 2; n++) {
        int col = w*32 + n*16 + lrow;
#pragma unroll
        for (int k = 0; k < 8; k++)
            WB2[n][k] = *(const bf16x8*)&W2t[(size_t)col*256 + k*32 + quad*8];
        b2col[n] = b2f32[col]; gcol[n] = g2[col]; bwcol[n] = bt2[col];
    }

    // phase 2: U = T@W2 — k split into two halves so only af[4] is live
    f32x4 a2[4][2];
#pragma unroll
    for (int rt = 0; rt < 4; rt++)
#pragma unroll
        for (int n = 0; n < 2; n++) { f32x4 z = {0.f,0.f,0.f,0.f}; a2[rt][n] = z; }
#pragma unroll
    for (int rt = 0; rt < 4; rt++) {
        {
            bf16x8 af[4];
#pragma unroll
            for (int k = 0; k < 4; k++)
                af[k] = *(const bf16x8*)&t_sm[(rt*16+lrow)*264 + k*32 + quad*8];
#pragma unroll
            for (int n = 0; n < 2; n++)
#pragma unroll
                for (int k = 0; k < 4; k++)
                    a2[rt][n] = __builtin_amdgcn_mfma_f32_16x16x32_bf16(af[k], WB2[n][k], a2[rt][n], 0, 0, 0);
        }
        {
            bf16x8 af[4];
#pragma unroll
            for (int k = 0; k < 4; k++)
                af[k] = *(const bf16x8*)&t_sm[(rt*16+lrow)*264 + (k+4)*32 + quad*8];
#pragma unroll
            for (int n = 0; n < 2; n++)
#pragma unroll
                for (int k = 0; k < 4; k++)
                    a2[rt][n] = __builtin_amdgcn_mfma_f32_16x16x32_bf16(af[k], WB2[n][k+4], a2[rt][n], 0, 0, 0);
        }
    }

    // +b2 +SC(prefetched), cross-wave LN partials
#pragma unroll
    for (int rt = 0; rt < 4; rt++)
#pragma unroll
        for (int r = 0; r < 4; r++) {
            float s = 0.f, sq = 0.f;
#pragma unroll
            for (int n = 0; n < 2; n++) {
                float v = a2[rt][n][r] + b2col[n] + scv[rt][r][n];
                a2[rt][n][r] = v; s += v; sq += v*v;
            }
#pragma unroll
            for (int off = 1; off < 16; off <<= 1) { s += __shfl_xor(s, off); sq += __shfl_xor(sq, off); }
            if (lrow == 0) { int ri = rt*16 + quad*4 + r; pls[w*64+ri] = s; plq[w*64+ri] = sq; }
        }
    __syncthreads();   // partials ready; h_sm/t_sm dead -> lt reuse OK
#pragma unroll
    for (int rt = 0; rt < 4; rt++)
#pragma unroll
        for (int r = 0; r < 4; r++) {
            int ri = rt*16 + quad*4 + r;
            float s  = pls[ri] + pls[64+ri] + pls[128+ri] + pls[192+ri];
            float sq = plq[ri] + plq[64+ri] + plq[128+ri] + plq[192+ri];
            float mean = s*(1.0f/128.0f);
            float var = sq*(1.0f/128.0f) - mean*mean;
            float rstd = rsqrtf(var + 1e-5f);
#pragma unroll
            for (int n = 0; n < 2; n++)
                lt[(w*32 + n*16 + lrow)*68 + ri] = (a2[rt][n][r]-mean)*rstd*gcol[n] + bwcol[n];
        }
    __syncthreads();
    {
        const int cch = t>>1, ph = (t&1)*32;
        const float4* sp = (const float4*)&lt[cch*68 + ph];
        float4* dp = (float4*)&out[((long)(bb*128 + cch))*36864 + p0 + ph];
#pragma unroll
        for (int q2 = 0; q2 < 8; q2++) dp[q2] = sp[q2];
    }
}

// ---------------------------------------------------------------------------
extern "C" void kernel_launch(void* const* d_in, const int* in_sizes, int n_in,
                              void* d_out, int out_size, void* d_ws, size_t ws_size,
                              hipStream_t stream)
{
    const float* x1     = (const float*)d_in[0];
    const float* x2     = (const float*)d_in[1];
    const float* Wq     = (const float*)d_in[2];
    const float* bq     = (const float*)d_in[3];
    const float* Wk     = (const float*)d_in[4];
    const float* bk     = (const float*)d_in[5];
    const float* Wv     = (const float*)d_in[6];
    const float* bv     = (const float*)d_in[7];
    const float* Wq2    = (const float*)d_in[8];
    const float* bq2    = (const float*)d_in[9];
    const float* Wk2    = (const float*)d_in[10];
    const float* bk2    = (const float*)d_in[11];
    const float* Wv2    = (const float*)d_in[12];
    const float* bv2    = (const float*)d_in[13];
    const float* Wproj  = (const float*)d_in[14];
    const float* bproj  = (const float*)d_in[15];
    const float* gproj  = (const float*)d_in[16];
    const float* bprojln= (const float*)d_in[17];
    const float* g1     = (const float*)d_in[18];
    const float* b1     = (const float*)d_in[19];
    const float* Wfc1   = (const float*)d_in[20];
    const float* bfc1   = (const float*)d_in[21];
    const float* Wfc2   = (const float*)d_in[22];
    const float* bfc2   = (const float*)d_in[23];
    const float* g2     = (const float*)d_in[24];
    const float* b2v    = (const float*)d_in[25];

    char* ws = (char*)d_ws;
    u16*  WTPROJ = (u16*)(ws + 0L);
    u16*  WTKV   = (u16*)(ws + 65536L);
    u16*  WTQ    = (u16*)(ws + 196608L);
    u16*  WTFC1  = (u16*)(ws + 229376L);
    u16*  WTFC2  = (u16*)(ws + 294912L);
    u16*  WTQ2   = (u16*)(ws + 360448L);
    u16*  WTK2V2 = (u16*)(ws + 393216L);
    float* BKVf  = (float*)(ws + 524288L);
    float* BK2V2f= (float*)(ws + 525312L);
    u16*  KG     = (u16*)(ws + 1048576L);
    u16*  QG     = (u16*)(ws + 1572864L);
    u16*  QG2    = (u16*)(ws + 1835008L);
    u16*  KV2    = (u16*)(ws + 2097152L);
    float* QGO   = (float*)(ws + 2621440L);
    float* KVW   = (float*)(ws + 3145728L);     // 8 MB, ends 11,534,336
    u16*  REGA   = (u16*)(ws + 12582912L);      // 75.5 MB: KV -> Q/H
    u16*  SC     = (u16*)(ws + 88080384L);      // 37.75 MB, ends 125,829,120
    u16*  Q_H    = REGA;

    setup_weights<<<1026, 256, 0, stream>>>(Wq, Wk, Wv, Wq2, Wk2, Wv2, Wproj, Wfc1, Wfc2,
                                            bk, bv, bk2, bv2,
                                            WTPROJ, WTKV, WTQ, WTFC1, WTFC2, WTQ2, WTK2V2,
                                            BKVf, BK2V2f);
    // fused: SC = gelu(LN(x1@Wproj)) AND KV = x1@Wkv from ONE staged tile
    proj_kv<<<1152, 256, 0, stream>>>(x1, WTPROJ, bproj, gproj, bprojln,
                                      WTKV, BKVf, SC, REGA, 2304);
    // global path
    avgpool_nchw<256><<<1024, 256, 0, stream>>>(x1, KG);
    avgpool_nchw<128><<<512, 256, 0, stream>>>(x2, QG);
    gemm_rw<128,128,0,0><<<16, 256, 0, stream>>>(nullptr, QG, WTQ2, bq2, QG2, 0.25f, 16);
    gemm_rw<256,256,0,0><<<16, 256, 0, stream>>>(nullptr, KG, WTK2V2, BK2V2f, KV2, 1.0f, 16);
    global_attn<<<2048, 256, 0, stream>>>(QG2, KV2, QGO);
    // windowed linear attention: per-window K^T V, then KV region dies
    window_kv<<<1024, 256, 0, stream>>>(REGA, KVW);
    // Q projection into dead KV region — persistent 1152 x 2
    gemm_rw<128,128,0,1><<<1152, 256, 0, stream>>>(x2, nullptr, WTQ, bq, Q_H, 0.25f, 2304);
    // ql = Q@(K^T V), + upsampled global, + LN  -> H (in-place over Q)
    window_out<<<1024, 256, 0, stream>>>(Q_H, KVW, QGO, g1, b1, Q_H);
    // fused MLP + final LN + f32 NCHW store
    mlp_fused<<<2304, 256, 0, stream>>>(Q_H, WTFC1, bfc1, WTFC2, bfc2, SC, g2, b2v, (float*)d_out, 2304);
}

// Round 10
// 633.401 us; speedup vs baseline: 1.0732x; 1.0732x over previous
//
#include <hip/hip_runtime.h>

// TransFusion on MI355X — round 14.
// r13 post-mortem: proj_kv hit 172 VGPR / occ 10% / 190us. Mechanism: the
// grid-stride loop made WtP/WtKV loads LOOP-INVARIANT -> LICM hoisted BOTH
// weight sets out of the loop (64+64 live). r10's phase-split worked because
// it was straight-line code, not because of the barrier.
// r14: keep the fusion (one staging feeds SC+KV, no XOUT bounce) but:
//  (1) one tile per block (grid=2304, no loop -> no LICM);
//  (2) sched_barrier(0) at the phase boundary (compile-time fence);
//  (3) phase-B n-halves in a #pragma unroll 1 loop (WBk depends on nh ->
//      one 64-VGPR half live at a time).
// Predict: proj_kv VGPR<=128, ~115-130us, total ~600-615us.

typedef unsigned short u16;
typedef unsigned int   u32;
typedef __bf16 bf16x8 __attribute__((ext_vector_type(8)));
typedef float  f32x4  __attribute__((ext_vector_type(4)));

__device__ __forceinline__ float b2f(u16 x) {
    union { u32 u; float f; } v; v.u = ((u32)x) << 16; return v.f;
}
__device__ __forceinline__ u16 f2b(float f) {
    union { float f; u32 u; } v; v.f = f;
    return (u16)((v.u + 0x7fffu + ((v.u >> 16) & 1u)) >> 16);
}
__device__ __forceinline__ u32 pk2(float x, float y) {
    return (u32)f2b(x) | ((u32)f2b(y) << 16);
}
// Branch-free A&S-7.1.26 gelu (~16 VALU, |err|<=1.5e-7).
__device__ __forceinline__ float gelu_fast(float x) {
    float z = x * 0.70710678118654752f;
    float a = fabsf(z);
    float t = __builtin_amdgcn_rcpf(fmaf(0.3275911f, a, 1.0f));
    float p = t*(0.254829592f + t*(-0.284496736f + t*(1.421413741f
              + t*(-1.453152027f + t*1.061405429f))));
    float e = __expf(-a*a);
    float er = copysignf(fmaf(-p, e, 1.0f), z);
    return 0.5f * x * (1.0f + er);
}
__device__ __forceinline__ void unpack8(uint4 r, float* v) {
    v[0] = b2f((u16)(r.x & 0xffff)); v[1] = b2f((u16)(r.x >> 16));
    v[2] = b2f((u16)(r.y & 0xffff)); v[3] = b2f((u16)(r.y >> 16));
    v[4] = b2f((u16)(r.z & 0xffff)); v[5] = b2f((u16)(r.z >> 16));
    v[6] = b2f((u16)(r.w & 0xffff)); v[7] = b2f((u16)(r.w >> 16));
}
__device__ __forceinline__ uint4 pack8(const float* v) {
    uint4 r;
    r.x = (u32)f2b(v[0]) | ((u32)f2b(v[1]) << 16);
    r.y = (u32)f2b(v[2]) | ((u32)f2b(v[3]) << 16);
    r.z = (u32)f2b(v[4]) | ((u32)f2b(v[5]) << 16);
    r.w = (u32)f2b(v[6]) | ((u32)f2b(v[7]) << 16);
    return r;
}

// ------------- one-time weight prep: f32 W[K][N] -> bf16 Wt[N][K] -----------
__launch_bounds__(256)
__global__ void setup_weights(const float* Wq, const float* Wk, const float* Wv,
    const float* Wq2, const float* Wk2, const float* Wv2, const float* Wproj,
    const float* Wfc1, const float* Wfc2, const float* bk, const float* bv,
    const float* bk2, const float* bv2,
    u16* wt_proj, u16* wt_kv, u16* wt_q, u16* wt_fc1, u16* wt_fc2,
    u16* wt_q2, u16* wt_k2v2, float* bkv, float* bk2v2)
{
    long i = (long)blockIdx.x*256 + threadIdx.x;
    if (i < 32768) { int k=(int)(i>>7), n=(int)(i&127); wt_proj[n*256+k]=f2b(Wproj[i]); return; } i -= 32768;
    if (i < 32768) { int k=(int)(i>>7), n=(int)(i&127); wt_kv[n*256+k]=f2b(Wk[i]); return; } i -= 32768;
    if (i < 32768) { int k=(int)(i>>7), n=(int)(i&127); wt_kv[(128+n)*256+k]=f2b(Wv[i]); return; } i -= 32768;
    if (i < 16384) { int k=(int)(i>>7), n=(int)(i&127); wt_q[n*128+k]=f2b(Wq[i]); return; } i -= 16384;
    if (i < 32768) { int k=(int)(i>>8), n=(int)(i&255); wt_fc1[n*128+k]=f2b(Wfc1[i]); return; } i -= 32768;
    if (i < 32768) { int k=(int)(i>>7), n=(int)(i&127); wt_fc2[n*256+k]=f2b(Wfc2[i]); return; } i -= 32768;
    if (i < 16384) { int k=(int)(i>>7), n=(int)(i&127); wt_q2[n*128+k]=f2b(Wq2[i]); return; } i -= 16384;
    if (i < 32768) { int k=(int)(i>>7), n=(int)(i&127); wt_k2v2[n*256+k]=f2b(Wk2[i]); return; } i -= 32768;
    if (i < 32768) { int k=(int)(i>>7), n=(int)(i&127); wt_k2v2[(128+n)*256+k]=f2b(Wv2[i]); return; } i -= 32768;
    if (i < 128) { bkv[i]=bk[i]; return; } i -= 128;
    if (i < 128) { bkv[128+i]=bv[i]; return; } i -= 128;
    if (i < 128) { bk2v2[i]=bk2[i]; return; } i -= 128;
    if (i < 128) { bk2v2[128+i]=bv2[i]; return; }
}

// ------ fused x1 projections: SC = gelu(LN(x1@Wproj+b)), KV = x1@Wkv+b ------
// ONE tile per block (no loop -> no LICM weight hoisting, the r13 failure).
// Phase A: NT=2 WTPROJ (64 VGPR), EPI=2 -> SC. sched_barrier(0) fence.
// Phase B: WTKV in two n-halves via #pragma unroll 1 (one 64-VGPR set live).
__launch_bounds__(256)
__global__ void proj_kv(const float* __restrict__ Af,
                        const u16* __restrict__ WtP, const float* __restrict__ biasP,
                        const float* __restrict__ gw, const float* __restrict__ bw,
                        const u16* __restrict__ WtKV, const float* __restrict__ biasKV,
                        u16* __restrict__ outSC, u16* __restrict__ outKV)
{
    constexpr int KD = 256, AST = KD + 8;
    __shared__ alignas(16) u16 a_sm[64*AST];
    __shared__ float pls[256], plq[256];
    const int t = threadIdx.x, w = t>>6, lane = t&63, lrow = lane&15, quad = lane>>4;

    const long row0 = (long)blockIdx.x*64;
    {   // NCHW staging, 2-channel packed (r11)
        const int bb = (int)(row0/36864); const long p0 = row0 % 36864;
        const int c0 = (t>>3)*2, pj = (t&7)*8;
#pragma unroll
        for (int cc = 0; cc < 4; cc++) {
            int c = c0 + cc*64;
            const float* s0 = Af + ((long)bb*KD + c)*36864 + p0 + pj;
            const float* s1 = s0 + 36864;
            float4 a0 = *(const float4*)s0, a1 = *(const float4*)(s0+4);
            float4 b0 = *(const float4*)s1, b1 = *(const float4*)(s1+4);
            *(u32*)&a_sm[(pj+0)*AST + c] = pk2(a0.x, b0.x);
            *(u32*)&a_sm[(pj+1)*AST + c] = pk2(a0.y, b0.y);
            *(u32*)&a_sm[(pj+2)*AST + c] = pk2(a0.z, b0.z);
            *(u32*)&a_sm[(pj+3)*AST + c] = pk2(a0.w, b0.w);
            *(u32*)&a_sm[(pj+4)*AST + c] = pk2(a1.x, b1.x);
            *(u32*)&a_sm[(pj+5)*AST + c] = pk2(a1.y, b1.y);
            *(u32*)&a_sm[(pj+6)*AST + c] = pk2(a1.z, b1.z);
            *(u32*)&a_sm[(pj+7)*AST + c] = pk2(a1.w, b1.w);
        }
    }
    __syncthreads();

    // ---- phase A: shortcut (ND=128, NT=2) ----
    {
        bf16x8 WBp[2][8];
        float bcolp[2], gcol[2], bwcol[2];
#pragma unroll
        for (int n = 0; n < 2; n++) {
            int col = w*32 + n*16 + lrow;
#pragma unroll
            for (int k = 0; k < 8; k++)
                WBp[n][k] = *(const bf16x8*)&WtP[(size_t)col*KD + k*32 + quad*8];
            bcolp[n] = biasP[col]; gcol[n] = gw[col]; bwcol[n] = bw[col];
        }
        f32x4 acc[4][2];
#pragma unroll
        for (int rt = 0; rt < 4; rt++)
#pragma unroll
            for (int n = 0; n < 2; n++) { f32x4 z = {0.f,0.f,0.f,0.f}; acc[rt][n] = z; }
#pragma unroll
        for (int rt = 0; rt < 4; rt++) {
            bf16x8 af[8];
#pragma unroll
            for (int k = 0; k < 8; k++)
                af[k] = *(const bf16x8*)&a_sm[(rt*16+lrow)*AST + k*32 + quad*8];
#pragma unroll
            for (int n = 0; n < 2; n++)
#pragma unroll
                for (int k = 0; k < 8; k++)
                    acc[rt][n] = __builtin_amdgcn_mfma_f32_16x16x32_bf16(af[k], WBp[n][k], acc[rt][n], 0, 0, 0);
        }
#pragma unroll
        for (int rt = 0; rt < 4; rt++)
#pragma unroll
            for (int r = 0; r < 4; r++) {
                float s = 0.f, sq = 0.f;
#pragma unroll
                for (int n = 0; n < 2; n++) {
                    float v = acc[rt][n][r] + bcolp[n];
                    acc[rt][n][r] = v; s += v; sq += v*v;
                }
#pragma unroll
                for (int off = 1; off < 16; off <<= 1) { s += __shfl_xor(s, off); sq += __shfl_xor(sq, off); }
                if (lrow == 0) { int ri = rt*16 + quad*4 + r; pls[w*64+ri] = s; plq[w*64+ri] = sq; }
            }
        __syncthreads();
#pragma unroll
        for (int rt = 0; rt < 4; rt++)
#pragma unroll
            for (int r = 0; r < 4; r++) {
                int ri = rt*16 + quad*4 + r;
                float s  = pls[ri] + pls[64+ri] + pls[128+ri] + pls[192+ri];
                float sq = plq[ri] + plq[64+ri] + plq[128+ri] + plq[192+ri];
                float mean = s*(1.0f/128.0f);
                float var = sq*(1.0f/128.0f) - mean*mean;
                float rstd = rsqrtf(var + 1e-5f);
#pragma unroll
                for (int n = 0; n < 2; n++) {
                    int col = w*32 + n*16 + lrow;
                    float y = (acc[rt][n][r]-mean)*rstd*gcol[n] + bwcol[n];
                    outSC[(row0+ri)*128 + col] = f2b(gelu_fast(y));
                }
            }
    }
    __syncthreads();
    __builtin_amdgcn_sched_barrier(0);   // fence: no phase-B loads above

    // ---- phase B: K|V (ND=256) in two n-halves, one 64-VGPR set live ----
#pragma unroll 1
    for (int nh = 0; nh < 2; nh++) {
        bf16x8 WBk[2][8];
        float bcolk[2];
#pragma unroll
        for (int n = 0; n < 2; n++) {
            int col = w*64 + nh*32 + n*16 + lrow;
#pragma unroll
            for (int k = 0; k < 8; k++)
                WBk[n][k] = *(const bf16x8*)&WtKV[(size_t)col*KD + k*32 + quad*8];
            bcolk[n] = biasKV[col];
        }
#pragma unroll
        for (int rt = 0; rt < 4; rt++) {
            bf16x8 af[8];
#pragma unroll
            for (int k = 0; k < 8; k++)
                af[k] = *(const bf16x8*)&a_sm[(rt*16+lrow)*AST + k*32 + quad*8];
            f32x4 acc[2];
#pragma unroll
            for (int n = 0; n < 2; n++) { f32x4 z = {0.f,0.f,0.f,0.f}; acc[n] = z; }
#pragma unroll
            for (int n = 0; n < 2; n++)
#pragma unroll
                for (int k = 0; k < 8; k++)
                    acc[n] = __builtin_amdgcn_mfma_f32_16x16x32_bf16(af[k], WBk[n][k], acc[n], 0, 0, 0);
#pragma unroll
            for (int n = 0; n < 2; n++) {
                int col = w*64 + nh*32 + n*16 + lrow;
#pragma unroll
                for (int r = 0; r < 4; r++)
                    outKV[(row0 + rt*16 + quad*4 + r)*256 + col] = f2b(acc[n][r] + bcolk[n]);
            }
        }
    }
}

// ---------------- register-weight MFMA GEMM ---------------------------------
// out[r][n] = epi(A[r][:] @ Wt[n][:] + bias[n]); 64-row tiles, grid-stride.
// NCHW_IN=1: A = Af (f32 [bb][KD][36864]); else A = Ab (bf16 row-major [*][KD]).
// EPI 0: bf16 out = (acc+bias)*scale.
template<int KD, int ND, int EPI, int NCHW_IN>
__launch_bounds__(256)
__global__ void gemm_rw(const float* __restrict__ Af, const u16* __restrict__ Ab,
                        const u16* __restrict__ Wt, const float* __restrict__ bias,
                        u16* __restrict__ out, float scale, int nTiles)
{
    constexpr int KS = KD/32, NW = ND/4, NT = NW/16, AST = KD + 8;
    __shared__ alignas(16) u16 a_sm[64*AST];
    const int t = threadIdx.x, w = t>>6, lane = t&63, lrow = lane&15, quad = lane>>4;

    bf16x8 WB[NT][KS];
    float bcol[NT];
#pragma unroll
    for (int n = 0; n < NT; n++) {
        int col = w*NW + n*16 + lrow;
#pragma unroll
        for (int k = 0; k < KS; k++)
            WB[n][k] = *(const bf16x8*)&Wt[(size_t)col*KD + k*32 + quad*8];
        bcol[n] = bias[col];
    }

    for (int tile = blockIdx.x; tile < nTiles; tile += gridDim.x) {
        const long row0 = (long)tile*64;
        __syncthreads();
        if (NCHW_IN) {
            const int bb = (int)(row0/36864); const long p0 = row0 % 36864;
            const int c0 = (t>>3)*2, pj = (t&7)*8;
#pragma unroll
            for (int cc = 0; cc < KD/64; cc++) {
                int c = c0 + cc*64;
                const float* s0 = Af + ((long)bb*KD + c)*36864 + p0 + pj;
                const float* s1 = s0 + 36864;
                float4 a0 = *(const float4*)s0, a1 = *(const float4*)(s0+4);
                float4 b0 = *(const float4*)s1, b1 = *(const float4*)(s1+4);
                *(u32*)&a_sm[(pj+0)*AST + c] = pk2(a0.x, b0.x);
                *(u32*)&a_sm[(pj+1)*AST + c] = pk2(a0.y, b0.y);
                *(u32*)&a_sm[(pj+2)*AST + c] = pk2(a0.z, b0.z);
                *(u32*)&a_sm[(pj+3)*AST + c] = pk2(a0.w, b0.w);
                *(u32*)&a_sm[(pj+4)*AST + c] = pk2(a1.x, b1.x);
                *(u32*)&a_sm[(pj+5)*AST + c] = pk2(a1.y, b1.y);
                *(u32*)&a_sm[(pj+6)*AST + c] = pk2(a1.z, b1.z);
                *(u32*)&a_sm[(pj+7)*AST + c] = pk2(a1.w, b1.w);
            }
        } else {
            const int am = t>>2, ak = (t&3)*(KD/4);
#pragma unroll
            for (int j = 0; j < KD/32; j++)
                *(uint4*)&a_sm[am*AST + ak + j*8] = *(const uint4*)&Ab[(row0+am)*KD + ak + j*8];
        }
        __syncthreads();

#pragma unroll
        for (int rt = 0; rt < 4; rt++) {
            bf16x8 af[KS];
#pragma unroll
            for (int k = 0; k < KS; k++)
                af[k] = *(const bf16x8*)&a_sm[(rt*16+lrow)*AST + k*32 + quad*8];
            f32x4 acc[NT];
#pragma unroll
            for (int n = 0; n < NT; n++) { f32x4 z = {0.f,0.f,0.f,0.f}; acc[n] = z; }
#pragma unroll
            for (int n = 0; n < NT; n++)
#pragma unroll
                for (int k = 0; k < KS; k++)
                    acc[n] = __builtin_amdgcn_mfma_f32_16x16x32_bf16(af[k], WB[n][k], acc[n], 0, 0, 0);
#pragma unroll
            for (int n = 0; n < NT; n++) {
                int col = w*NW + n*16 + lrow;
#pragma unroll
                for (int r = 0; r < 4; r++)
                    out[(row0 + rt*16 + quad*4 + r)*ND + col] = f2b((acc[n][r] + bcol[n]) * scale);
            }
        }
    }
}

// ---------------- 12x12 avgpool over f32 NCHW -> bf16 -----------------------
template<int C>
__launch_bounds__(256)
__global__ void avgpool_nchw(const float* __restrict__ X, u16* __restrict__ out)
{
    int blk = blockIdx.x;
    int bb = blk / C, c = blk % C;
    int t = threadIdx.x;
    int wy = t >> 4, wx = t & 15;
    const float* base = X + ((long)(bb*C + c))*36864;
    float s = 0.f;
    for (int py = 0; py < 12; py++) {
        long ro = (long)(wy*12+py)*192 + wx*12;
#pragma unroll
        for (int px = 0; px < 12; px++) s += base[ro + px];
    }
    out[((long)(bb*256 + t))*C + c] = f2b(s * (1.0f/144.0f));
}

// ---------------- global-path softmax attention (tiny) ----------------------
__launch_bounds__(256)
__global__ void global_attn(const u16* __restrict__ qg, const u16* __restrict__ kv,
                            float* __restrict__ qgo)
{
    int t = threadIdx.x;
    int wvq = t >> 6, lane = t & 63;
    int bid = blockIdx.x;
    int qb = bid & 63, bh = bid >> 6;
    int bb = bh >> 3, h = bh & 7;
    int q = qb*4 + wvq;

    const u16* qrow = qg + ((long)(bb*256 + q))*128 + h*16;
    float qv[16];
#pragma unroll
    for (int d = 0; d < 16; d++) qv[d] = b2f(qrow[d]);

    float s[4];
#pragma unroll
    for (int jj = 0; jj < 4; jj++) {
        int j = jj*64 + lane;
        const u16* krow = kv + ((long)(bb*256 + j))*256 + h*16;
        float a = 0.f;
#pragma unroll
        for (int d = 0; d < 16; d++) a += qv[d] * b2f(krow[d]);
        s[jj] = a;
    }
    float m = fmaxf(fmaxf(s[0], s[1]), fmaxf(s[2], s[3]));
#pragma unroll
    for (int off = 1; off < 64; off <<= 1) m = fmaxf(m, __shfl_xor(m, off));
    float p[4]; float lsum = 0.f;
#pragma unroll
    for (int jj = 0; jj < 4; jj++) { p[jj] = expf(s[jj] - m); lsum += p[jj]; }
#pragma unroll
    for (int off = 1; off < 64; off <<= 1) lsum += __shfl_xor(lsum, off);

    float acc[16];
#pragma unroll
    for (int d = 0; d < 16; d++) acc[d] = 0.f;
#pragma unroll
    for (int jj = 0; jj < 4; jj++) {
        int j = jj*64 + lane;
        const u16* vrow = kv + ((long)(bb*256 + j))*256 + 128 + h*16;
#pragma unroll
        for (int d = 0; d < 16; d++) acc[d] += p[jj] * b2f(vrow[d]);
    }
#pragma unroll
    for (int d = 0; d < 16; d++) {
        float x = acc[d];
#pragma unroll
        for (int off = 1; off < 64; off <<= 1) x += __shfl_xor(x, off);
        acc[d] = x;
    }
    if (lane == 0) {
        float inv = 1.0f / lsum;
        float* dst = qgo + ((long)(bb*256 + q))*128 + h*16;
#pragma unroll
        for (int d = 0; d < 16; d++) dst[d] = acc[d] * inv;
    }
}

// ---------------- per-window K^T V (16x16 per head) -------------------------
__launch_bounds__(256)
__global__ void window_kv(const u16* __restrict__ KV, float* __restrict__ KVw)
{
    __shared__ alignas(16) u16 kvs[72*256];
    int t = threadIdx.x;
    int wid = blockIdx.x;
    int bb = wid >> 8, wy = (wid >> 4) & 15, wx = wid & 15;
    int h = t >> 5, rem = t & 31, ii = rem >> 1, j0 = (rem & 1)*8;
    float acc[8];
#pragma unroll
    for (int j = 0; j < 8; j++) acc[j] = 0.f;

    for (int chunk = 0; chunk < 2; chunk++) {
        __syncthreads();
        for (int pass = 0; pass < 5; pass++) {
            int nn = pass*16 + (t >> 4);
            if (nn < 72) {
                int n = chunk*72 + nn;
                int py = n/12, px = n%12;
                long row = (long)bb*36864 + (long)(wy*12+py)*192 + wx*12+px;
                int ch = (t & 15)*16;
                *(uint4*)&kvs[nn*256 + ch]     = *(const uint4*)&KV[row*256 + ch];
                *(uint4*)&kvs[nn*256 + ch + 8] = *(const uint4*)&KV[row*256 + ch + 8];
            }
        }
        __syncthreads();
        for (int nn = 0; nn < 72; nn++) {
            float kvv = b2f(kvs[nn*256 + h*16 + ii]);
            uint4 vr = *(const uint4*)&kvs[nn*256 + 128 + h*16 + j0];
            float vv[8]; unpack8(vr, vv);
#pragma unroll
            for (int j = 0; j < 8; j++) acc[j] += kvv * vv[j];
        }
    }
    float* dst = KVw + (((long)wid*8 + h)*16 + ii)*16 + j0;
#pragma unroll
    for (int j = 0; j < 8; j++) dst[j] = acc[j];
}

// ---- per-window ql = Q@(K^T V), + bilinear-upsampled global out, + LN ------
__launch_bounds__(256)
__global__ void window_out(const u16* __restrict__ Q, const float* __restrict__ KVw,
                           const float* __restrict__ qgo, const float* __restrict__ gw,
                           const float* __restrict__ bw, u16* __restrict__ Hout)
{
    __shared__ alignas(16) u16 qs[144*136];
    __shared__ alignas(16) float kvs[8*264];
    int t = threadIdx.x;
    int wid = blockIdx.x;
    int bb = wid >> 8, wy = (wid >> 4) & 15, wx = wid & 15;

    for (int pass = 0; pass < 9; pass++) {
        int n = pass*16 + (t >> 4);
        int py = n/12, px = n%12;
        long row = (long)bb*36864 + (long)(wy*12+py)*192 + wx*12+px;
        int ch = (t & 15)*8;
        *(uint4*)&qs[n*136 + ch] = *(const uint4*)&Q[row*128 + ch];
    }
    {
        const float* src = KVw + (long)wid*2048;
        for (int e = t; e < 2048; e += 256) {
            int hh = e >> 8, rem2 = e & 255;
            kvs[hh*264 + rem2] = src[e];
        }
    }
    __syncthreads();
    int td = t & 15;
    int h = td & 7, j0 = (td >> 3)*8;
    int cbase = h*16 + j0;
    float gv8[8], bv8[8];
#pragma unroll
    for (int j = 0; j < 8; j++) { gv8[j] = gw[cbase+j]; bv8[j] = bw[cbase+j]; }

    for (int pass = 0; pass < 9; pass++) {
        int pi = pass*16 + (t >> 4);
        int py = pi/12, px = pi%12;
        int y = wy*12+py, x = wx*12+px;
        float acc[8];
#pragma unroll
        for (int j = 0; j < 8; j++) acc[j] = 0.f;
#pragma unroll
        for (int i = 0; i < 16; i++) {
            float qv = b2f(qs[pi*136 + h*16 + i]);
            const float* kp = &kvs[h*264 + i*16 + j0];
            float4 ka = *(const float4*)kp;
            float4 kb = *(const float4*)(kp + 4);
            acc[0] += qv*ka.x; acc[1] += qv*ka.y; acc[2] += qv*ka.z; acc[3] += qv*ka.w;
            acc[4] += qv*kb.x; acc[5] += qv*kb.y; acc[6] += qv*kb.z; acc[7] += qv*kb.w;
        }
        float syf = y * (15.0f/191.0f);
        int y0 = (int)syf; float fy = syf - y0; int y1 = min(y0+1, 15);
        float sxf = x * (15.0f/191.0f);
        int x0 = (int)sxf; float fx = sxf - x0; int x1 = min(x0+1, 15);
        const float* g00 = qgo + (((long)bb*16 + y0)*16 + x0)*128 + cbase;
        const float* g01 = qgo + (((long)bb*16 + y0)*16 + x1)*128 + cbase;
        const float* g10 = qgo + (((long)bb*16 + y1)*16 + x0)*128 + cbase;
        const float* g11 = qgo + (((long)bb*16 + y1)*16 + x1)*128 + cbase;
        float w00 = (1.f-fy)*(1.f-fx), w01 = (1.f-fy)*fx, w10 = fy*(1.f-fx), w11 = fy*fx;
        float v8[8];
        float sum = 0.f, sq = 0.f;
#pragma unroll
        for (int j = 0; j < 8; j++) {
            float gval = w00*g00[j] + w01*g01[j] + w10*g10[j] + w11*g11[j];
            float xv = acc[j] + gval;
            v8[j] = xv; sum += xv; sq += xv*xv;
        }
#pragma unroll
        for (int off = 1; off < 16; off <<= 1) { sum += __shfl_xor(sum, off); sq += __shfl_xor(sq, off); }
        float mean = sum * (1.0f/128.0f);
        float var = sq * (1.0f/128.0f) - mean*mean;
        float rstd = rsqrtf(var + 1e-5f);
        float o8[8];
#pragma unroll
        for (int j = 0; j < 8; j++) o8[j] = (v8[j]-mean)*rstd*gv8[j] + bv8[j];
        long orow = (long)bb*36864 + (long)y*192 + x;
        *(uint4*)&Hout[orow*128 + cbase] = pack8(o8);
    }
}

// ------- fused MLP: U = gelu(H@W1+b1)@W2+b2; out = LN(U+SC) -> f32 NCHW -----
// Phase-split weight residency (r10) + SC register prefetch (r11).
__launch_bounds__(256)
__global__ void mlp_fused(const u16* __restrict__ H, const u16* __restrict__ W1t,
                          const float* __restrict__ b1f, const u16* __restrict__ W2t,
                          const float* __restrict__ b2f32, const u16* __restrict__ SC,
                          const float* __restrict__ g2, const float* __restrict__ bt2,
                          float* __restrict__ out, int nTiles)
{
    __shared__ alignas(16) char sm[53248];
    u16* h_sm  = (u16*)sm;              // 64 x 136 u16 (17408 B)
    u16* t_sm  = (u16*)(sm + 17408);    // 64 x 264 u16 (33792 B)
    float* pls = (float*)(sm + 51200);  // 4 x 64
    float* plq = (float*)(sm + 52224);  // 4 x 64
    float* lt  = (float*)sm;            // 128 x 68 f32 (34816 B) — after phase 2

    const int t = threadIdx.x, w = t>>6, lane = t&63, lrow = lane&15, quad = lane>>4;

    const long row0 = (long)blockIdx.x*64;
    const int bb = (int)(row0/36864); const long p0 = row0 % 36864;

    // SC prefetch — issued first so the (L3-resident) loads drain under
    // phase 1.
    float scv[4][4][2];
#pragma unroll
    for (int rt = 0; rt < 4; rt++)
#pragma unroll
        for (int r = 0; r < 4; r++)
#pragma unroll
            for (int n = 0; n < 2; n++)
                scv[rt][r][n] = b2f(SC[(row0 + rt*16 + quad*4 + r)*128 + w*32 + n*16 + lrow]);

    // ---- phase-1 weights only (64 VGPR) ----
    bf16x8 WB1[4][4];
    float b1col[4];
#pragma unroll
    for (int n = 0; n < 4; n++) {
        int col = w*64 + n*16 + lrow;
#pragma unroll
        for (int k = 0; k < 4; k++)
            WB1[n][k] = *(const bf16x8*)&W1t[(size_t)col*128 + k*32 + quad*8];
        b1col[n] = b1f[col];
    }

    // stage H
    {
        const int am = t>>2, ak = (t&3)*32;
#pragma unroll
        for (int j = 0; j < 4; j++)
            *(uint4*)&h_sm[am*136 + ak + j*8] = *(const uint4*)&H[(row0+am)*128 + ak + j*8];
    }
    __syncthreads();

    // phase 1: T = gelu(H@W1+b1) -> t_sm
#pragma unroll
    for (int rt = 0; rt < 4; rt++) {
        bf16x8 af[4];
#pragma unroll
        for (int k = 0; k < 4; k++)
            af[k] = *(const bf16x8*)&h_sm[(rt*16+lrow)*136 + k*32 + quad*8];
        f32x4 a1[4];
#pragma unroll
        for (int n = 0; n < 4; n++) { f32x4 z = {0.f,0.f,0.f,0.f}; a1[n] = z; }
#pragma unroll
        for (int n = 0; n < 4; n++)
#pragma unroll
            for (int k = 0; k < 4; k++)
                a1[n] = __builtin_amdgcn_mfma_f32_16x16x32_bf16(af[k], WB1[n][k], a1[n], 0, 0, 0);
#pragma unroll
        for (int n = 0; n < 4; n++)
#pragma unroll
            for (int r = 0; r < 4; r++)
                t_sm[(rt*16+quad*4+r)*264 + w*64 + n*16 + lrow] = f2b(gelu_fast(a1[n][r] + b1col[n]));
    }
    __syncthreads();   // phase boundary
    __builtin_amdgcn_sched_barrier(0);

    // ---- phase-2 weights into the freed registers (64 VGPR) ----
    bf16x8 WB2[2][8];
    float b2col[2], gcol[2], bwcol[2];
#pragma unroll
    for (int n = 0; n < 2; n++) {
        int col = w*32 + n*16 + lrow;
#pragma unroll
        for (int k = 0; k < 8; k++)
            WB2[n][k] = *(const bf16x8*)&W2t[(size_t)col*256 + k*32 + quad*8];
        b2col[n] = b2f32[col]; gcol[n] = g2[col]; bwcol[n] = bt2[col];
    }

    // phase 2: U = T@W2 — k split into two halves so only af[4] is live
    f32x4 a2[4][2];
#pragma unroll
    for (int rt = 0; rt < 4; rt++)
#pragma unroll
        for (int n = 0; n < 2; n++) { f32x4 z = {0.f,0.f,0.f,0.f}; a2[rt][n] = z; }
#pragma unroll
    for (int rt = 0; rt < 4; rt++) {
        {
            bf16x8 af[4];
#pragma unroll
            for (int k = 0; k < 4; k++)
                af[k] = *(const bf16x8*)&t_sm[(rt*16+lrow)*264 + k*32 + quad*8];
#pragma unroll
            for (int n = 0; n < 2; n++)
#pragma unroll
                for (int k = 0; k < 4; k++)
                    a2[rt][n] = __builtin_amdgcn_mfma_f32_16x16x32_bf16(af[k], WB2[n][k], a2[rt][n], 0, 0, 0);
        }
        {
            bf16x8 af[4];
#pragma unroll
            for (int k = 0; k < 4; k++)
                af[k] = *(const bf16x8*)&t_sm[(rt*16+lrow)*264 + (k+4)*32 + quad*8];
#pragma unroll
            for (int n = 0; n < 2; n++)
#pragma unroll
                for (int k = 0; k < 4; k++)
                    a2[rt][n] = __builtin_amdgcn_mfma_f32_16x16x32_bf16(af[k], WB2[n][k+4], a2[rt][n], 0, 0, 0);
        }
    }

    // +b2 +SC(prefetched), cross-wave LN partials
#pragma unroll
    for (int rt = 0; rt < 4; rt++)
#pragma unroll
        for (int r = 0; r < 4; r++) {
            float s = 0.f, sq = 0.f;
#pragma unroll
            for (int n = 0; n < 2; n++) {
                float v = a2[rt][n][r] + b2col[n] + scv[rt][r][n];
                a2[rt][n][r] = v; s += v; sq += v*v;
            }
#pragma unroll
            for (int off = 1; off < 16; off <<= 1) { s += __shfl_xor(s, off); sq += __shfl_xor(sq, off); }
            if (lrow == 0) { int ri = rt*16 + quad*4 + r; pls[w*64+ri] = s; plq[w*64+ri] = sq; }
        }
    __syncthreads();   // partials ready; h_sm/t_sm dead -> lt reuse OK
#pragma unroll
    for (int rt = 0; rt < 4; rt++)
#pragma unroll
        for (int r = 0; r < 4; r++) {
            int ri = rt*16 + quad*4 + r;
            float s  = pls[ri] + pls[64+ri] + pls[128+ri] + pls[192+ri];
            float sq = plq[ri] + plq[64+ri] + plq[128+ri] + plq[192+ri];
            float mean = s*(1.0f/128.0f);
            float var = sq*(1.0f/128.0f) - mean*mean;
            float rstd = rsqrtf(var + 1e-5f);
#pragma unroll
            for (int n = 0; n < 2; n++)
                lt[(w*32 + n*16 + lrow)*68 + ri] = (a2[rt][n][r]-mean)*rstd*gcol[n] + bwcol[n];
        }
    __syncthreads();
    {
        const int cch = t>>1, ph = (t&1)*32;
        const float4* sp = (const float4*)&lt[cch*68 + ph];
        float4* dp = (float4*)&out[((long)(bb*128 + cch))*36864 + p0 + ph];
#pragma unroll
        for (int q2 = 0; q2 < 8; q2++) dp[q2] = sp[q2];
    }
}

// ---------------------------------------------------------------------------
extern "C" void kernel_launch(void* const* d_in, const int* in_sizes, int n_in,
                              void* d_out, int out_size, void* d_ws, size_t ws_size,
                              hipStream_t stream)
{
    const float* x1     = (const float*)d_in[0];
    const float* x2     = (const float*)d_in[1];
    const float* Wq     = (const float*)d_in[2];
    const float* bq     = (const float*)d_in[3];
    const float* Wk     = (const float*)d_in[4];
    const float* bk     = (const float*)d_in[5];
    const float* Wv     = (const float*)d_in[6];
    const float* bv     = (const float*)d_in[7];
    const float* Wq2    = (const float*)d_in[8];
    const float* bq2    = (const float*)d_in[9];
    const float* Wk2    = (const float*)d_in[10];
    const float* bk2    = (const float*)d_in[11];
    const float* Wv2    = (const float*)d_in[12];
    const float* bv2    = (const float*)d_in[13];
    const float* Wproj  = (const float*)d_in[14];
    const float* bproj  = (const float*)d_in[15];
    const float* gproj  = (const float*)d_in[16];
    const float* bprojln= (const float*)d_in[17];
    const float* g1     = (const float*)d_in[18];
    const float* b1     = (const float*)d_in[19];
    const float* Wfc1   = (const float*)d_in[20];
    const float* bfc1   = (const float*)d_in[21];
    const float* Wfc2   = (const float*)d_in[22];
    const float* bfc2   = (const float*)d_in[23];
    const float* g2     = (const float*)d_in[24];
    const float* b2v    = (const float*)d_in[25];

    char* ws = (char*)d_ws;
    u16*  WTPROJ = (u16*)(ws + 0L);
    u16*  WTKV   = (u16*)(ws + 65536L);
    u16*  WTQ    = (u16*)(ws + 196608L);
    u16*  WTFC1  = (u16*)(ws + 229376L);
    u16*  WTFC2  = (u16*)(ws + 294912L);
    u16*  WTQ2   = (u16*)(ws + 360448L);
    u16*  WTK2V2 = (u16*)(ws + 393216L);
    float* BKVf  = (float*)(ws + 524288L);
    float* BK2V2f= (float*)(ws + 525312L);
    u16*  KG     = (u16*)(ws + 1048576L);
    u16*  QG     = (u16*)(ws + 1572864L);
    u16*  QG2    = (u16*)(ws + 1835008L);
    u16*  KV2    = (u16*)(ws + 2097152L);
    float* QGO   = (float*)(ws + 2621440L);
    float* KVW   = (float*)(ws + 3145728L);     // 8 MB, ends 11,534,336
    u16*  REGA   = (u16*)(ws + 12582912L);      // 75.5 MB: KV -> Q/H
    u16*  SC     = (u16*)(ws + 88080384L);      // 37.75 MB, ends 125,829,120
    u16*  Q_H    = REGA;

    setup_weights<<<1026, 256, 0, stream>>>(Wq, Wk, Wv, Wq2, Wk2, Wv2, Wproj, Wfc1, Wfc2,
                                            bk, bv, bk2, bv2,
                                            WTPROJ, WTKV, WTQ, WTFC1, WTFC2, WTQ2, WTK2V2,
                                            BKVf, BK2V2f);
    // fused: SC = gelu(LN(x1@Wproj)) AND KV = x1@Wkv from ONE staged tile —
    // one tile per block (no LICM).
    proj_kv<<<2304, 256, 0, stream>>>(x1, WTPROJ, bproj, gproj, bprojln,
                                      WTKV, BKVf, SC, REGA);
    // global path
    avgpool_nchw<256><<<1024, 256, 0, stream>>>(x1, KG);
    avgpool_nchw<128><<<512, 256, 0, stream>>>(x2, QG);
    gemm_rw<128,128,0,0><<<16, 256, 0, stream>>>(nullptr, QG, WTQ2, bq2, QG2, 0.25f, 16);
    gemm_rw<256,256,0,0><<<16, 256, 0, stream>>>(nullptr, KG, WTK2V2, BK2V2f, KV2, 1.0f, 16);
    global_attn<<<2048, 256, 0, stream>>>(QG2, KV2, QGO);
    // windowed linear attention: per-window K^T V, then KV region dies
    window_kv<<<1024, 256, 0, stream>>>(REGA, KVW);
    // Q projection into dead KV region — persistent 1152 x 2
    gemm_rw<128,128,0,1><<<1152, 256, 0, stream>>>(x2, nullptr, WTQ, bq, Q_H, 0.25f, 2304);
    // ql = Q@(K^T V), + upsampled global, + LN  -> H (in-place over Q)
    window_out<<<1024, 256, 0, stream>>>(Q_H, KVW, QGO, g1, b1, Q_H);
    // fused MLP + final LN + f32 NCHW store
    mlp_fused<<<2304, 256, 0, stream>>>(Q_H, WTFC1, bfc1, WTFC2, bfc2, SC, g2, b2v, (float*)d_out, 2304);
}

// Round 11
// 616.272 us; speedup vs baseline: 1.1030x; 1.0278x over previous
//
#include <hip/hip_runtime.h>

// TransFusion on MI355X — round 15.
// r14: proj_kv 108 VGPR / 139us / occ 20% — latency+VALU bound (all pipes
// >=75% idle). Two fixes, all in proj_kv (+shared helpers):
//  (1) v_cvt_pk_bf16_f32 (1 inst, RNE == our f2b bit-trick for normals)
//      replaces ~8-int-op packed conversions: staging pk2, SC/KV epilogue
//      pairs. Also rides along in gemm_rw staging + window_out pack8.
//  (2) pipelined weight issue: WBp loads BEFORE the staging barrier, WBk
//      half-0 loads BEFORE the LN-partials barrier (the compiler's
//      vmcnt(0)-before-s_barrier drains them under the barrier wait);
//      sched_barrier(0) fences stop hoisting into regions where another
//      64-VGPR weight set is live. Redundant post-phase-A barrier dropped.
// Predict: proj_kv ~108-118us, VGPR<=128, VALUBusy ~19%; total ~600-612us.

typedef unsigned short u16;
typedef unsigned int   u32;
typedef __bf16 bf16x8 __attribute__((ext_vector_type(8)));
typedef float  f32x4  __attribute__((ext_vector_type(4)));

__device__ __forceinline__ float b2f(u16 x) {
    union { u32 u; float f; } v; v.u = ((u32)x) << 16; return v.f;
}
__device__ __forceinline__ u16 f2b(float f) {
    union { float f; u32 u; } v; v.f = f;
    return (u16)((v.u + 0x7fffu + ((v.u >> 16) & 1u)) >> 16);
}
// HW packed f32->bf16 (RNE, identical to f2b for normal values): 1 VALU inst
// vs ~8 for two bit-trick conversions + pack.
__device__ __forceinline__ u32 cvtpk(float lo, float hi) {
    u32 r;
    asm("v_cvt_pk_bf16_f32 %0, %1, %2" : "=v"(r) : "v"(lo), "v"(hi));
    return r;
}
// Branch-free A&S-7.1.26 gelu (~16 VALU, |err|<=1.5e-7).
__device__ __forceinline__ float gelu_fast(float x) {
    float z = x * 0.70710678118654752f;
    float a = fabsf(z);
    float t = __builtin_amdgcn_rcpf(fmaf(0.3275911f, a, 1.0f));
    float p = t*(0.254829592f + t*(-0.284496736f + t*(1.421413741f
              + t*(-1.453152027f + t*1.061405429f))));
    float e = __expf(-a*a);
    float er = copysignf(fmaf(-p, e, 1.0f), z);
    return 0.5f * x * (1.0f + er);
}
__device__ __forceinline__ void unpack8(uint4 r, float* v) {
    v[0] = b2f((u16)(r.x & 0xffff)); v[1] = b2f((u16)(r.x >> 16));
    v[2] = b2f((u16)(r.y & 0xffff)); v[3] = b2f((u16)(r.y >> 16));
    v[4] = b2f((u16)(r.z & 0xffff)); v[5] = b2f((u16)(r.z >> 16));
    v[6] = b2f((u16)(r.w & 0xffff)); v[7] = b2f((u16)(r.w >> 16));
}
__device__ __forceinline__ uint4 pack8(const float* v) {
    uint4 r;
    r.x = cvtpk(v[0], v[1]);
    r.y = cvtpk(v[2], v[3]);
    r.z = cvtpk(v[4], v[5]);
    r.w = cvtpk(v[6], v[7]);
    return r;
}

// ------------- one-time weight prep: f32 W[K][N] -> bf16 Wt[N][K] -----------
__launch_bounds__(256)
__global__ void setup_weights(const float* Wq, const float* Wk, const float* Wv,
    const float* Wq2, const float* Wk2, const float* Wv2, const float* Wproj,
    const float* Wfc1, const float* Wfc2, const float* bk, const float* bv,
    const float* bk2, const float* bv2,
    u16* wt_proj, u16* wt_kv, u16* wt_q, u16* wt_fc1, u16* wt_fc2,
    u16* wt_q2, u16* wt_k2v2, float* bkv, float* bk2v2)
{
    long i = (long)blockIdx.x*256 + threadIdx.x;
    if (i < 32768) { int k=(int)(i>>7), n=(int)(i&127); wt_proj[n*256+k]=f2b(Wproj[i]); return; } i -= 32768;
    if (i < 32768) { int k=(int)(i>>7), n=(int)(i&127); wt_kv[n*256+k]=f2b(Wk[i]); return; } i -= 32768;
    if (i < 32768) { int k=(int)(i>>7), n=(int)(i&127); wt_kv[(128+n)*256+k]=f2b(Wv[i]); return; } i -= 32768;
    if (i < 16384) { int k=(int)(i>>7), n=(int)(i&127); wt_q[n*128+k]=f2b(Wq[i]); return; } i -= 16384;
    if (i < 32768) { int k=(int)(i>>8), n=(int)(i&255); wt_fc1[n*128+k]=f2b(Wfc1[i]); return; } i -= 32768;
    if (i < 32768) { int k=(int)(i>>7), n=(int)(i&127); wt_fc2[n*256+k]=f2b(Wfc2[i]); return; } i -= 32768;
    if (i < 16384) { int k=(int)(i>>7), n=(int)(i&127); wt_q2[n*128+k]=f2b(Wq2[i]); return; } i -= 16384;
    if (i < 32768) { int k=(int)(i>>7), n=(int)(i&127); wt_k2v2[n*256+k]=f2b(Wk2[i]); return; } i -= 32768;
    if (i < 32768) { int k=(int)(i>>7), n=(int)(i&127); wt_k2v2[(128+n)*256+k]=f2b(Wv2[i]); return; } i -= 32768;
    if (i < 128) { bkv[i]=bk[i]; return; } i -= 128;
    if (i < 128) { bkv[128+i]=bv[i]; return; } i -= 128;
    if (i < 128) { bk2v2[i]=bk2[i]; return; } i -= 128;
    if (i < 128) { bk2v2[128+i]=bv2[i]; return; }
}

// ------ fused x1 projections: SC = gelu(LN(x1@Wproj+b)), KV = x1@Wkv+b ------
// ONE tile per block (no loop -> no LICM). Pipelined weight issue: each
// 64-VGPR weight set is issued BEFORE the preceding barrier so its L2
// latency drains under the barrier's vmcnt(0) wait. sched_barrier(0)
// fences keep sets from coexisting.
__launch_bounds__(256)
__global__ void proj_kv(const float* __restrict__ Af,
                        const u16* __restrict__ WtP, const float* __restrict__ biasP,
                        const float* __restrict__ gw, const float* __restrict__ bw,
                        const u16* __restrict__ WtKV, const float* __restrict__ biasKV,
                        u16* __restrict__ outSC, u16* __restrict__ outKV)
{
    constexpr int KD = 256, AST = KD + 8;
    __shared__ alignas(16) u16 a_sm[64*AST];
    __shared__ float pls[256], plq[256];
    const int t = threadIdx.x, w = t>>6, lane = t&63, lrow = lane&15, quad = lane>>4;

    const long row0 = (long)blockIdx.x*64;
    {   // NCHW staging, 2-channel packed via cvt_pk
        const int bb = (int)(row0/36864); const long p0 = row0 % 36864;
        const int c0 = (t>>3)*2, pj = (t&7)*8;
#pragma unroll
        for (int cc = 0; cc < 4; cc++) {
            int c = c0 + cc*64;
            const float* s0 = Af + ((long)bb*KD + c)*36864 + p0 + pj;
            const float* s1 = s0 + 36864;
            float4 a0 = *(const float4*)s0, a1 = *(const float4*)(s0+4);
            float4 b0 = *(const float4*)s1, b1 = *(const float4*)(s1+4);
            *(u32*)&a_sm[(pj+0)*AST + c] = cvtpk(a0.x, b0.x);
            *(u32*)&a_sm[(pj+1)*AST + c] = cvtpk(a0.y, b0.y);
            *(u32*)&a_sm[(pj+2)*AST + c] = cvtpk(a0.z, b0.z);
            *(u32*)&a_sm[(pj+3)*AST + c] = cvtpk(a0.w, b0.w);
            *(u32*)&a_sm[(pj+4)*AST + c] = cvtpk(a1.x, b1.x);
            *(u32*)&a_sm[(pj+5)*AST + c] = cvtpk(a1.y, b1.y);
            *(u32*)&a_sm[(pj+6)*AST + c] = cvtpk(a1.z, b1.z);
            *(u32*)&a_sm[(pj+7)*AST + c] = cvtpk(a1.w, b1.w);
        }
    }
    __builtin_amdgcn_sched_barrier(0);   // seal staging ILP region

    // phase-A weights issued pre-barrier: drain under the barrier wait
    bf16x8 WBp[2][8];
    float bcolp[2], gcol[2], bwcol[2];
#pragma unroll
    for (int n = 0; n < 2; n++) {
        int col = w*32 + n*16 + lrow;
#pragma unroll
        for (int k = 0; k < 8; k++)
            WBp[n][k] = *(const bf16x8*)&WtP[(size_t)col*KD + k*32 + quad*8];
        bcolp[n] = biasP[col]; gcol[n] = gw[col]; bwcol[n] = bw[col];
    }
    __syncthreads();

    // ---- phase A MFMA: SC = x1 @ Wproj ----
    f32x4 acc[4][2];
#pragma unroll
    for (int rt = 0; rt < 4; rt++)
#pragma unroll
        for (int n = 0; n < 2; n++) { f32x4 z = {0.f,0.f,0.f,0.f}; acc[rt][n] = z; }
#pragma unroll
    for (int rt = 0; rt < 4; rt++) {
        bf16x8 af[8];
#pragma unroll
        for (int k = 0; k < 8; k++)
            af[k] = *(const bf16x8*)&a_sm[(rt*16+lrow)*AST + k*32 + quad*8];
#pragma unroll
        for (int n = 0; n < 2; n++)
#pragma unroll
            for (int k = 0; k < 8; k++)
                acc[rt][n] = __builtin_amdgcn_mfma_f32_16x16x32_bf16(af[k], WBp[n][k], acc[rt][n], 0, 0, 0);
    }
    __builtin_amdgcn_sched_barrier(0);   // WBp dead past here; nothing hoists up

    // cross-wave LN partials
#pragma unroll
    for (int rt = 0; rt < 4; rt++)
#pragma unroll
        for (int r = 0; r < 4; r++) {
            float s = 0.f, sq = 0.f;
#pragma unroll
            for (int n = 0; n < 2; n++) {
                float v = acc[rt][n][r] + bcolp[n];
                acc[rt][n][r] = v; s += v; sq += v*v;
            }
#pragma unroll
            for (int off = 1; off < 16; off <<= 1) { s += __shfl_xor(s, off); sq += __shfl_xor(sq, off); }
            if (lrow == 0) { int ri = rt*16 + quad*4 + r; pls[w*64+ri] = s; plq[w*64+ri] = sq; }
        }

    // phase-B half-0 weights issued before the partials barrier (drain under it)
    bf16x8 WBk[2][8];
    float bcolk[2];
#pragma unroll
    for (int n = 0; n < 2; n++) {
        int col = w*64 + n*16 + lrow;
#pragma unroll
        for (int k = 0; k < 8; k++)
            WBk[n][k] = *(const bf16x8*)&WtKV[(size_t)col*KD + k*32 + quad*8];
        bcolk[n] = biasKV[col];
    }
    __syncthreads();

    // LN finalize + gelu + paired SC stores
#pragma unroll
    for (int rt = 0; rt < 4; rt++)
#pragma unroll
        for (int r = 0; r < 4; r++) {
            int ri = rt*16 + quad*4 + r;
            float s  = pls[ri] + pls[64+ri] + pls[128+ri] + pls[192+ri];
            float sq = plq[ri] + plq[64+ri] + plq[128+ri] + plq[192+ri];
            float mean = s*(1.0f/128.0f);
            float var = sq*(1.0f/128.0f) - mean*mean;
            float rstd = rsqrtf(var + 1e-5f);
            float y0 = (acc[rt][0][r]-mean)*rstd*gcol[0] + bwcol[0];
            float y1 = (acc[rt][1][r]-mean)*rstd*gcol[1] + bwcol[1];
            u32 pr = cvtpk(gelu_fast(y0), gelu_fast(y1));
            long o = (row0+ri)*128 + w*32 + lrow;
            outSC[o]      = (u16)pr;
            outSC[o + 16] = (u16)(pr >> 16);
        }
    __builtin_amdgcn_sched_barrier(0);

    // ---- phase B half 0: KV cols [w*64, w*64+32) (weights preloaded) ----
#pragma unroll
    for (int rt = 0; rt < 4; rt++) {
        bf16x8 af[8];
#pragma unroll
        for (int k = 0; k < 8; k++)
            af[k] = *(const bf16x8*)&a_sm[(rt*16+lrow)*AST + k*32 + quad*8];
        f32x4 a2[2];
#pragma unroll
        for (int n = 0; n < 2; n++) { f32x4 z = {0.f,0.f,0.f,0.f}; a2[n] = z; }
#pragma unroll
        for (int n = 0; n < 2; n++)
#pragma unroll
            for (int k = 0; k < 8; k++)
                a2[n] = __builtin_amdgcn_mfma_f32_16x16x32_bf16(af[k], WBk[n][k], a2[n], 0, 0, 0);
#pragma unroll
        for (int r = 0; r < 4; r++) {
            u32 pr = cvtpk(a2[0][r] + bcolk[0], a2[1][r] + bcolk[1]);
            long o = (row0 + rt*16 + quad*4 + r)*256 + w*64 + lrow;
            outKV[o]      = (u16)pr;
            outKV[o + 16] = (u16)(pr >> 16);
        }
    }
    __builtin_amdgcn_sched_barrier(0);   // half-1 loads stay below half-0 MFMA

    // ---- phase B half 1: KV cols [w*64+32, w*64+64) ----
#pragma unroll
    for (int n = 0; n < 2; n++) {
        int col = w*64 + 32 + n*16 + lrow;
#pragma unroll
        for (int k = 0; k < 8; k++)
            WBk[n][k] = *(const bf16x8*)&WtKV[(size_t)col*KD + k*32 + quad*8];
        bcolk[n] = biasKV[col];
    }
#pragma unroll
    for (int rt = 0; rt < 4; rt++) {
        bf16x8 af[8];
#pragma unroll
        for (int k = 0; k < 8; k++)
            af[k] = *(const bf16x8*)&a_sm[(rt*16+lrow)*AST + k*32 + quad*8];
        f32x4 a2[2];
#pragma unroll
        for (int n = 0; n < 2; n++) { f32x4 z = {0.f,0.f,0.f,0.f}; a2[n] = z; }
#pragma unroll
        for (int n = 0; n < 2; n++)
#pragma unroll
            for (int k = 0; k < 8; k++)
                a2[n] = __builtin_amdgcn_mfma_f32_16x16x32_bf16(af[k], WBk[n][k], a2[n], 0, 0, 0);
#pragma unroll
        for (int r = 0; r < 4; r++) {
            u32 pr = cvtpk(a2[0][r] + bcolk[0], a2[1][r] + bcolk[1]);
            long o = (row0 + rt*16 + quad*4 + r)*256 + w*64 + 32 + lrow;
            outKV[o]      = (u16)pr;
            outKV[o + 16] = (u16)(pr >> 16);
        }
    }
}

// ---------------- register-weight MFMA GEMM ---------------------------------
// out[r][n] = epi(A[r][:] @ Wt[n][:] + bias[n]); 64-row tiles, grid-stride.
// NCHW_IN=1: A = Af (f32 [bb][KD][36864]); else A = Ab (bf16 row-major [*][KD]).
// EPI 0: bf16 out = (acc+bias)*scale.
template<int KD, int ND, int EPI, int NCHW_IN>
__launch_bounds__(256)
__global__ void gemm_rw(const float* __restrict__ Af, const u16* __restrict__ Ab,
                        const u16* __restrict__ Wt, const float* __restrict__ bias,
                        u16* __restrict__ out, float scale, int nTiles)
{
    constexpr int KS = KD/32, NW = ND/4, NT = NW/16, AST = KD + 8;
    __shared__ alignas(16) u16 a_sm[64*AST];
    const int t = threadIdx.x, w = t>>6, lane = t&63, lrow = lane&15, quad = lane>>4;

    bf16x8 WB[NT][KS];
    float bcol[NT];
#pragma unroll
    for (int n = 0; n < NT; n++) {
        int col = w*NW + n*16 + lrow;
#pragma unroll
        for (int k = 0; k < KS; k++)
            WB[n][k] = *(const bf16x8*)&Wt[(size_t)col*KD + k*32 + quad*8];
        bcol[n] = bias[col];
    }

    for (int tile = blockIdx.x; tile < nTiles; tile += gridDim.x) {
        const long row0 = (long)tile*64;
        __syncthreads();
        if (NCHW_IN) {
            const int bb = (int)(row0/36864); const long p0 = row0 % 36864;
            const int c0 = (t>>3)*2, pj = (t&7)*8;
#pragma unroll
            for (int cc = 0; cc < KD/64; cc++) {
                int c = c0 + cc*64;
                const float* s0 = Af + ((long)bb*KD + c)*36864 + p0 + pj;
                const float* s1 = s0 + 36864;
                float4 a0 = *(const float4*)s0, a1 = *(const float4*)(s0+4);
                float4 b0 = *(const float4*)s1, b1 = *(const float4*)(s1+4);
                *(u32*)&a_sm[(pj+0)*AST + c] = cvtpk(a0.x, b0.x);
                *(u32*)&a_sm[(pj+1)*AST + c] = cvtpk(a0.y, b0.y);
                *(u32*)&a_sm[(pj+2)*AST + c] = cvtpk(a0.z, b0.z);
                *(u32*)&a_sm[(pj+3)*AST + c] = cvtpk(a0.w, b0.w);
                *(u32*)&a_sm[(pj+4)*AST + c] = cvtpk(a1.x, b1.x);
                *(u32*)&a_sm[(pj+5)*AST + c] = cvtpk(a1.y, b1.y);
                *(u32*)&a_sm[(pj+6)*AST + c] = cvtpk(a1.z, b1.z);
                *(u32*)&a_sm[(pj+7)*AST + c] = cvtpk(a1.w, b1.w);
            }
        } else {
            const int am = t>>2, ak = (t&3)*(KD/4);
#pragma unroll
            for (int j = 0; j < KD/32; j++)
                *(uint4*)&a_sm[am*AST + ak + j*8] = *(const uint4*)&Ab[(row0+am)*KD + ak + j*8];
        }
        __syncthreads();

#pragma unroll
        for (int rt = 0; rt < 4; rt++) {
            bf16x8 af[KS];
#pragma unroll
            for (int k = 0; k < KS; k++)
                af[k] = *(const bf16x8*)&a_sm[(rt*16+lrow)*AST + k*32 + quad*8];
            f32x4 acc[NT];
#pragma unroll
            for (int n = 0; n < NT; n++) { f32x4 z = {0.f,0.f,0.f,0.f}; acc[n] = z; }
#pragma unroll
            for (int n = 0; n < NT; n++)
#pragma unroll
                for (int k = 0; k < KS; k++)
                    acc[n] = __builtin_amdgcn_mfma_f32_16x16x32_bf16(af[k], WB[n][k], acc[n], 0, 0, 0);
#pragma unroll
            for (int n = 0; n < NT; n++) {
                int col = w*NW + n*16 + lrow;
#pragma unroll
                for (int r = 0; r < 4; r++)
                    out[(row0 + rt*16 + quad*4 + r)*ND + col] = f2b((acc[n][r] + bcol[n]) * scale);
            }
        }
    }
}

// ---------------- 12x12 avgpool over f32 NCHW -> bf16 -----------------------
template<int C>
__launch_bounds__(256)
__global__ void avgpool_nchw(const float* __restrict__ X, u16* __restrict__ out)
{
    int blk = blockIdx.x;
    int bb = blk / C, c = blk % C;
    int t = threadIdx.x;
    int wy = t >> 4, wx = t & 15;
    const float* base = X + ((long)(bb*C + c))*36864;
    float s = 0.f;
    for (int py = 0; py < 12; py++) {
        long ro = (long)(wy*12+py)*192 + wx*12;
#pragma unroll
        for (int px = 0; px < 12; px++) s += base[ro + px];
    }
    out[((long)(bb*256 + t))*C + c] = f2b(s * (1.0f/144.0f));
}

// ---------------- global-path softmax attention (tiny) ----------------------
__launch_bounds__(256)
__global__ void global_attn(const u16* __restrict__ qg, const u16* __restrict__ kv,
                            float* __restrict__ qgo)
{
    int t = threadIdx.x;
    int wvq = t >> 6, lane = t & 63;
    int bid = blockIdx.x;
    int qb = bid & 63, bh = bid >> 6;
    int bb = bh >> 3, h = bh & 7;
    int q = qb*4 + wvq;

    const u16* qrow = qg + ((long)(bb*256 + q))*128 + h*16;
    float qv[16];
#pragma unroll
    for (int d = 0; d < 16; d++) qv[d] = b2f(qrow[d]);

    float s[4];
#pragma unroll
    for (int jj = 0; jj < 4; jj++) {
        int j = jj*64 + lane;
        const u16* krow = kv + ((long)(bb*256 + j))*256 + h*16;
        float a = 0.f;
#pragma unroll
        for (int d = 0; d < 16; d++) a += qv[d] * b2f(krow[d]);
        s[jj] = a;
    }
    float m = fmaxf(fmaxf(s[0], s[1]), fmaxf(s[2], s[3]));
#pragma unroll
    for (int off = 1; off < 64; off <<= 1) m = fmaxf(m, __shfl_xor(m, off));
    float p[4]; float lsum = 0.f;
#pragma unroll
    for (int jj = 0; jj < 4; jj++) { p[jj] = expf(s[jj] - m); lsum += p[jj]; }
#pragma unroll
    for (int off = 1; off < 64; off <<= 1) lsum += __shfl_xor(lsum, off);

    float acc[16];
#pragma unroll
    for (int d = 0; d < 16; d++) acc[d] = 0.f;
#pragma unroll
    for (int jj = 0; jj < 4; jj++) {
        int j = jj*64 + lane;
        const u16* vrow = kv + ((long)(bb*256 + j))*256 + 128 + h*16;
#pragma unroll
        for (int d = 0; d < 16; d++) acc[d] += p[jj] * b2f(vrow[d]);
    }
#pragma unroll
    for (int d = 0; d < 16; d++) {
        float x = acc[d];
#pragma unroll
        for (int off = 1; off < 64; off <<= 1) x += __shfl_xor(x, off);
        acc[d] = x;
    }
    if (lane == 0) {
        float inv = 1.0f / lsum;
        float* dst = qgo + ((long)(bb*256 + q))*128 + h*16;
#pragma unroll
        for (int d = 0; d < 16; d++) dst[d] = acc[d] * inv;
    }
}

// ---------------- per-window K^T V (16x16 per head) -------------------------
__launch_bounds__(256)
__global__ void window_kv(const u16* __restrict__ KV, float* __restrict__ KVw)
{
    __shared__ alignas(16) u16 kvs[72*256];
    int t = threadIdx.x;
    int wid = blockIdx.x;
    int bb = wid >> 8, wy = (wid >> 4) & 15, wx = wid & 15;
    int h = t >> 5, rem = t & 31, ii = rem >> 1, j0 = (rem & 1)*8;
    float acc[8];
#pragma unroll
    for (int j = 0; j < 8; j++) acc[j] = 0.f;

    for (int chunk = 0; chunk < 2; chunk++) {
        __syncthreads();
        for (int pass = 0; pass < 5; pass++) {
            int nn = pass*16 + (t >> 4);
            if (nn < 72) {
                int n = chunk*72 + nn;
                int py = n/12, px = n%12;
                long row = (long)bb*36864 + (long)(wy*12+py)*192 + wx*12+px;
                int ch = (t & 15)*16;
                *(uint4*)&kvs[nn*256 + ch]     = *(const uint4*)&KV[row*256 + ch];
                *(uint4*)&kvs[nn*256 + ch + 8] = *(const uint4*)&KV[row*256 + ch + 8];
            }
        }
        __syncthreads();
        for (int nn = 0; nn < 72; nn++) {
            float kvv = b2f(kvs[nn*256 + h*16 + ii]);
            uint4 vr = *(const uint4*)&kvs[nn*256 + 128 + h*16 + j0];
            float vv[8]; unpack8(vr, vv);
#pragma unroll
            for (int j = 0; j < 8; j++) acc[j] += kvv * vv[j];
        }
    }
    float* dst = KVw + (((long)wid*8 + h)*16 + ii)*16 + j0;
#pragma unroll
    for (int j = 0; j < 8; j++) dst[j] = acc[j];
}

// ---- per-window ql = Q@(K^T V), + bilinear-upsampled global out, + LN ------
__launch_bounds__(256)
__global__ void window_out(const u16* __restrict__ Q, const float* __restrict__ KVw,
                           const float* __restrict__ qgo, const float* __restrict__ gw,
                           const float* __restrict__ bw, u16* __restrict__ Hout)
{
    __shared__ alignas(16) u16 qs[144*136];
    __shared__ alignas(16) float kvs[8*264];
    int t = threadIdx.x;
    int wid = blockIdx.x;
    int bb = wid >> 8, wy = (wid >> 4) & 15, wx = wid & 15;

    for (int pass = 0; pass < 9; pass++) {
        int n = pass*16 + (t >> 4);
        int py = n/12, px = n%12;
        long row = (long)bb*36864 + (long)(wy*12+py)*192 + wx*12+px;
        int ch = (t & 15)*8;
        *(uint4*)&qs[n*136 + ch] = *(const uint4*)&Q[row*128 + ch];
    }
    {
        const float* src = KVw + (long)wid*2048;
        for (int e = t; e < 2048; e += 256) {
            int hh = e >> 8, rem2 = e & 255;
            kvs[hh*264 + rem2] = src[e];
        }
    }
    __syncthreads();
    int td = t & 15;
    int h = td & 7, j0 = (td >> 3)*8;
    int cbase = h*16 + j0;
    float gv8[8], bv8[8];
#pragma unroll
    for (int j = 0; j < 8; j++) { gv8[j] = gw[cbase+j]; bv8[j] = bw[cbase+j]; }

    for (int pass = 0; pass < 9; pass++) {
        int pi = pass*16 + (t >> 4);
        int py = pi/12, px = pi%12;
        int y = wy*12+py, x = wx*12+px;
        float acc[8];
#pragma unroll
        for (int j = 0; j < 8; j++) acc[j] = 0.f;
#pragma unroll
        for (int i = 0; i < 16; i++) {
            float qv = b2f(qs[pi*136 + h*16 + i]);
            const float* kp = &kvs[h*264 + i*16 + j0];
            float4 ka = *(const float4*)kp;
            float4 kb = *(const float4*)(kp + 4);
            acc[0] += qv*ka.x; acc[1] += qv*ka.y; acc[2] += qv*ka.z; acc[3] += qv*ka.w;
            acc[4] += qv*kb.x; acc[5] += qv*kb.y; acc[6] += qv*kb.z; acc[7] += qv*kb.w;
        }
        float syf = y * (15.0f/191.0f);
        int y0 = (int)syf; float fy = syf - y0; int y1 = min(y0+1, 15);
        float sxf = x * (15.0f/191.0f);
        int x0 = (int)sxf; float fx = sxf - x0; int x1 = min(x0+1, 15);
        const float* g00 = qgo + (((long)bb*16 + y0)*16 + x0)*128 + cbase;
        const float* g01 = qgo + (((long)bb*16 + y0)*16 + x1)*128 + cbase;
        const float* g10 = qgo + (((long)bb*16 + y1)*16 + x0)*128 + cbase;
        const float* g11 = qgo + (((long)bb*16 + y1)*16 + x1)*128 + cbase;
        float w00 = (1.f-fy)*(1.f-fx), w01 = (1.f-fy)*fx, w10 = fy*(1.f-fx), w11 = fy*fx;
        float v8[8];
        float sum = 0.f, sq = 0.f;
#pragma unroll
        for (int j = 0; j < 8; j++) {
            float gval = w00*g00[j] + w01*g01[j] + w10*g10[j] + w11*g11[j];
            float xv = acc[j] + gval;
            v8[j] = xv; sum += xv; sq += xv*xv;
        }
#pragma unroll
        for (int off = 1; off < 16; off <<= 1) { sum += __shfl_xor(sum, off); sq += __shfl_xor(sq, off); }
        float mean = sum * (1.0f/128.0f);
        float var = sq * (1.0f/128.0f) - mean*mean;
        float rstd = rsqrtf(var + 1e-5f);
        float o8[8];
#pragma unroll
        for (int j = 0; j < 8; j++) o8[j] = (v8[j]-mean)*rstd*gv8[j] + bv8[j];
        long orow = (long)bb*36864 + (long)y*192 + x;
        *(uint4*)&Hout[orow*128 + cbase] = pack8(o8);
    }
}

// ------- fused MLP: U = gelu(H@W1+b1)@W2+b2; out = LN(U+SC) -> f32 NCHW -----
// Phase-split weight residency (r10) + SC register prefetch (r11).
__launch_bounds__(256)
__global__ void mlp_fused(const u16* __restrict__ H, const u16* __restrict__ W1t,
                          const float* __restrict__ b1f, const u16* __restrict__ W2t,
                          const float* __restrict__ b2f32, const u16* __restrict__ SC,
                          const float* __restrict__ g2, const float* __restrict__ bt2,
                          float* __restrict__ out, int nTiles)
{
    __shared__ alignas(16) char sm[53248];
    u16* h_sm  = (u16*)sm;              // 64 x 136 u16 (17408 B)
    u16* t_sm  = (u16*)(sm + 17408);    // 64 x 264 u16 (33792 B)
    float* pls = (float*)(sm + 51200);  // 4 x 64
    float* plq = (float*)(sm + 52224);  // 4 x 64
    float* lt  = (float*)sm;            // 128 x 68 f32 (34816 B) — after phase 2

    const int t = threadIdx.x, w = t>>6, lane = t&63, lrow = lane&15, quad = lane>>4;

    const long row0 = (long)blockIdx.x*64;
    const int bb = (int)(row0/36864); const long p0 = row0 % 36864;

    // SC prefetch — issued first so the (L3-resident) loads drain under
    // phase 1.
    float scv[4][4][2];
#pragma unroll
    for (int rt = 0; rt < 4; rt++)
#pragma unroll
        for (int r = 0; r < 4; r++)
#pragma unroll
            for (int n = 0; n < 2; n++)
                scv[rt][r][n] = b2f(SC[(row0 + rt*16 + quad*4 + r)*128 + w*32 + n*16 + lrow]);

    // ---- phase-1 weights only (64 VGPR) ----
    bf16x8 WB1[4][4];
    float b1col[4];
#pragma unroll
    for (int n = 0; n < 4; n++) {
        int col = w*64 + n*16 + lrow;
#pragma unroll
        for (int k = 0; k < 4; k++)
            WB1[n][k] = *(const bf16x8*)&W1t[(size_t)col*128 + k*32 + quad*8];
        b1col[n] = b1f[col];
    }

    // stage H
    {
        const int am = t>>2, ak = (t&3)*32;
#pragma unroll
        for (int j = 0; j < 4; j++)
            *(uint4*)&h_sm[am*136 + ak + j*8] = *(const uint4*)&H[(row0+am)*128 + ak + j*8];
    }
    __syncthreads();

    // phase 1: T = gelu(H@W1+b1) -> t_sm
#pragma unroll
    for (int rt = 0; rt < 4; rt++) {
        bf16x8 af[4];
#pragma unroll
        for (int k = 0; k < 4; k++)
            af[k] = *(const bf16x8*)&h_sm[(rt*16+lrow)*136 + k*32 + quad*8];
        f32x4 a1[4];
#pragma unroll
        for (int n = 0; n < 4; n++) { f32x4 z = {0.f,0.f,0.f,0.f}; a1[n] = z; }
#pragma unroll
        for (int n = 0; n < 4; n++)
#pragma unroll
            for (int k = 0; k < 4; k++)
                a1[n] = __builtin_amdgcn_mfma_f32_16x16x32_bf16(af[k], WB1[n][k], a1[n], 0, 0, 0);
#pragma unroll
        for (int n = 0; n < 4; n++)
#pragma unroll
            for (int r = 0; r < 4; r++)
                t_sm[(rt*16+quad*4+r)*264 + w*64 + n*16 + lrow] = f2b(gelu_fast(a1[n][r] + b1col[n]));
    }
    __syncthreads();   // phase boundary
    __builtin_amdgcn_sched_barrier(0);

    // ---- phase-2 weights into the freed registers (64 VGPR) ----
    bf16x8 WB2[2][8];
    float b2col[2], gcol[2], bwcol[2];
#pragma unroll
    for (int n = 0; n < 2; n++) {
        int col = w*32 + n*16 + lrow;
#pragma unroll
        for (int k = 0; k < 8; k++)
            WB2[n][k] = *(const bf16x8*)&W2t[(size_t)col*256 + k*32 + quad*8];
        b2col[n] = b2f32[col]; gcol[n] = g2[col]; bwcol[n] = bt2[col];
    }

    // phase 2: U = T@W2 — k split into two halves so only af[4] is live
    f32x4 a2[4][2];
#pragma unroll
    for (int rt = 0; rt < 4; rt++)
#pragma unroll
        for (int n = 0; n < 2; n++) { f32x4 z = {0.f,0.f,0.f,0.f}; a2[rt][n] = z; }
#pragma unroll
    for (int rt = 0; rt < 4; rt++) {
        {
            bf16x8 af[4];
#pragma unroll
            for (int k = 0; k < 4; k++)
                af[k] = *(const bf16x8*)&t_sm[(rt*16+lrow)*264 + k*32 + quad*8];
#pragma unroll
            for (int n = 0; n < 2; n++)
#pragma unroll
                for (int k = 0; k < 4; k++)
                    a2[rt][n] = __builtin_amdgcn_mfma_f32_16x16x32_bf16(af[k], WB2[n][k], a2[rt][n], 0, 0, 0);
        }
        {
            bf16x8 af[4];
#pragma unroll
            for (int k = 0; k < 4; k++)
                af[k] = *(const bf16x8*)&t_sm[(rt*16+lrow)*264 + (k+4)*32 + quad*8];
#pragma unroll
            for (int n = 0; n < 2; n++)
#pragma unroll
                for (int k = 0; k < 4; k++)
                    a2[rt][n] = __builtin_amdgcn_mfma_f32_16x16x32_bf16(af[k], WB2[n][k+4], a2[rt][n], 0, 0, 0);
        }
    }

    // +b2 +SC(prefetched), cross-wave LN partials
#pragma unroll
    for (int rt = 0; rt < 4; rt++)
#pragma unroll
        for (int r = 0; r < 4; r++) {
            float s = 0.f, sq = 0.f;
#pragma unroll
            for (int n = 0; n < 2; n++) {
                float v = a2[rt][n][r] + b2col[n] + scv[rt][r][n];
                a2[rt][n][r] = v; s += v; sq += v*v;
            }
#pragma unroll
            for (int off = 1; off < 16; off <<= 1) { s += __shfl_xor(s, off); sq += __shfl_xor(sq, off); }
            if (lrow == 0) { int ri = rt*16 + quad*4 + r; pls[w*64+ri] = s; plq[w*64+ri] = sq; }
        }
    __syncthreads();   // partials ready; h_sm/t_sm dead -> lt reuse OK
#pragma unroll
    for (int rt = 0; rt < 4; rt++)
#pragma unroll
        for (int r = 0; r < 4; r++) {
            int ri = rt*16 + quad*4 + r;
            float s  = pls[ri] + pls[64+ri] + pls[128+ri] + pls[192+ri];
            float sq = plq[ri] + plq[64+ri] + plq[128+ri] + plq[192+ri];
            float mean = s*(1.0f/128.0f);
            float var = sq*(1.0f/128.0f) - mean*mean;
            float rstd = rsqrtf(var + 1e-5f);
#pragma unroll
            for (int n = 0; n < 2; n++)
                lt[(w*32 + n*16 + lrow)*68 + ri] = (a2[rt][n][r]-mean)*rstd*gcol[n] + bwcol[n];
        }
    __syncthreads();
    {
        const int cch = t>>1, ph = (t&1)*32;
        const float4* sp = (const float4*)&lt[cch*68 + ph];
        float4* dp = (float4*)&out[((long)(bb*128 + cch))*36864 + p0 + ph];
#pragma unroll
        for (int q2 = 0; q2 < 8; q2++) dp[q2] = sp[q2];
    }
}

// ---------------------------------------------------------------------------
extern "C" void kernel_launch(void* const* d_in, const int* in_sizes, int n_in,
                              void* d_out, int out_size, void* d_ws, size_t ws_size,
                              hipStream_t stream)
{
    const float* x1     = (const float*)d_in[0];
    const float* x2     = (const float*)d_in[1];
    const float* Wq     = (const float*)d_in[2];
    const float* bq     = (const float*)d_in[3];
    const float* Wk     = (const float*)d_in[4];
    const float* bk     = (const float*)d_in[5];
    const float* Wv     = (const float*)d_in[6];
    const float* bv     = (const float*)d_in[7];
    const float* Wq2    = (const float*)d_in[8];
    const float* bq2    = (const float*)d_in[9];
    const float* Wk2    = (const float*)d_in[10];
    const float* bk2    = (const float*)d_in[11];
    const float* Wv2    = (const float*)d_in[12];
    const float* bv2    = (const float*)d_in[13];
    const float* Wproj  = (const float*)d_in[14];
    const float* bproj  = (const float*)d_in[15];
    const float* gproj  = (const float*)d_in[16];
    const float* bprojln= (const float*)d_in[17];
    const float* g1     = (const float*)d_in[18];
    const float* b1     = (const float*)d_in[19];
    const float* Wfc1   = (const float*)d_in[20];
    const float* bfc1   = (const float*)d_in[21];
    const float* Wfc2   = (const float*)d_in[22];
    const float* bfc2   = (const float*)d_in[23];
    const float* g2     = (const float*)d_in[24];
    const float* b2v    = (const float*)d_in[25];

    char* ws = (char*)d_ws;
    u16*  WTPROJ = (u16*)(ws + 0L);
    u16*  WTKV   = (u16*)(ws + 65536L);
    u16*  WTQ    = (u16*)(ws + 196608L);
    u16*  WTFC1  = (u16*)(ws + 229376L);
    u16*  WTFC2  = (u16*)(ws + 294912L);
    u16*  WTQ2   = (u16*)(ws + 360448L);
    u16*  WTK2V2 = (u16*)(ws + 393216L);
    float* BKVf  = (float*)(ws + 524288L);
    float* BK2V2f= (float*)(ws + 525312L);
    u16*  KG     = (u16*)(ws + 1048576L);
    u16*  QG     = (u16*)(ws + 1572864L);
    u16*  QG2    = (u16*)(ws + 1835008L);
    u16*  KV2    = (u16*)(ws + 2097152L);
    float* QGO   = (float*)(ws + 2621440L);
    float* KVW   = (float*)(ws + 3145728L);     // 8 MB, ends 11,534,336
    u16*  REGA   = (u16*)(ws + 12582912L);      // 75.5 MB: KV -> Q/H
    u16*  SC     = (u16*)(ws + 88080384L);      // 37.75 MB, ends 125,829,120
    u16*  Q_H    = REGA;

    setup_weights<<<1026, 256, 0, stream>>>(Wq, Wk, Wv, Wq2, Wk2, Wv2, Wproj, Wfc1, Wfc2,
                                            bk, bv, bk2, bv2,
                                            WTPROJ, WTKV, WTQ, WTFC1, WTFC2, WTQ2, WTK2V2,
                                            BKVf, BK2V2f);
    // fused: SC = gelu(LN(x1@Wproj)) AND KV = x1@Wkv from ONE staged tile —
    // one tile per block (no LICM), pipelined weight issue.
    proj_kv<<<2304, 256, 0, stream>>>(x1, WTPROJ, bproj, gproj, bprojln,
                                      WTKV, BKVf, SC, REGA);
    // global path
    avgpool_nchw<256><<<1024, 256, 0, stream>>>(x1, KG);
    avgpool_nchw<128><<<512, 256, 0, stream>>>(x2, QG);
    gemm_rw<128,128,0,0><<<16, 256, 0, stream>>>(nullptr, QG, WTQ2, bq2, QG2, 0.25f, 16);
    gemm_rw<256,256,0,0><<<16, 256, 0, stream>>>(nullptr, KG, WTK2V2, BK2V2f, KV2, 1.0f, 16);
    global_attn<<<2048, 256, 0, stream>>>(QG2, KV2, QGO);
    // windowed linear attention: per-window K^T V, then KV region dies
    window_kv<<<1024, 256, 0, stream>>>(REGA, KVW);
    // Q projection into dead KV region — persistent 1152 x 2
    gemm_rw<128,128,0,1><<<1152, 256, 0, stream>>>(x2, nullptr, WTQ, bq, Q_H, 0.25f, 2304);
    // ql = Q@(K^T V), + upsampled global, + LN  -> H (in-place over Q)
    window_out<<<1024, 256, 0, stream>>>(Q_H, KVW, QGO, g1, b1, Q_H);
    // fused MLP + final LN + f32 NCHW store
    mlp_fused<<<2304, 256, 0, stream>>>(Q_H, WTFC1, bfc1, WTFC2, bfc2, SC, g2, b2v, (float*)d_out, 2304);
}